// Round 12
// baseline (238.747 us; speedup 1.0000x reference)
//
#include <hip/hip_runtime.h>

// GNN encoder, B=256, N=32, F=256, fully-connected edges, 2 passes.
// bf16 MFMA 16x16x32, fp32 accum.
// R12: edge v13 — barrier-free, LDS-free. Each wave builds its MFMA
// A-fragments (relu(U'+V)) directly in registers from per-lane global loads;
// B streamed from the L2-resident pre-swizzled weight image (1-step prefetch).
// MLP chains (R10) + merged prep (R11) unchanged.

typedef short bf16x8 __attribute__((ext_vector_type(8)));
typedef float f32x4 __attribute__((ext_vector_type(4)));
typedef unsigned short ushort_t;

__device__ __forceinline__ unsigned short f2bf(float f) {
    unsigned u = __float_as_uint(f);
    u += 0x7fff + ((u >> 16) & 1);   // RNE
    return (unsigned short)(u >> 16);
}
__device__ __forceinline__ float lo16f(unsigned w) { return __uint_as_float(w << 16); }
__device__ __forceinline__ float hi16f(unsigned w) { return __uint_as_float(w & 0xffff0000u); }
__device__ __forceinline__ unsigned cvt_pk_bf16(float lo, float hi) {
    unsigned r;
    asm volatile("v_cvt_pk_bf16_f32 %0, %1, %2" : "=v"(r) : "v"(lo), "v"(hi));
    return r;
}
__device__ __forceinline__ void gload16(const void* g, void* l) {
    __builtin_amdgcn_global_load_lds(
        (const __attribute__((address_space(1))) void*)g,
        (__attribute__((address_space(3))) void*)l, 16, 0, 0);
}

// ---------------------------------------------------------------------------
// Weight prep (blocks 0..55) + x conversion (blocks 56..1079), merged.
// Weight image: idx = kq*8192 + n*32 + (kc ^ ((n>>1)&3))*8 + (k&7), kq=k>>5.
__global__ __launch_bounds__(256) void prep_all(
    const float* __restrict__ w_in1, const float* __restrict__ w_in2,
    const float* __restrict__ w_e1,  const float* __restrict__ w_e2,
    const float* __restrict__ w_n1,  const float* __restrict__ w_n2,
    ushort_t* __restrict__ dst,
    const float* __restrict__ x, ushort_t* __restrict__ xb)
{
    __shared__ ushort_t tile[32][264];
    const int t = threadIdx.x;
    if (blockIdx.x >= 56) {
        const int i = (blockIdx.x - 56) * 256 + t;   // 1024 blocks cover 262144
        const float4* p = (const float4*)x + (size_t)i * 2;
        float4 a = p[0], b = p[1];
        ushort4 o0 = make_ushort4(f2bf(a.x), f2bf(a.y), f2bf(a.z), f2bf(a.w));
        ushort4 o1 = make_ushort4(f2bf(b.x), f2bf(b.y), f2bf(b.z), f2bf(b.w));
        ((ushort4*)xb)[(size_t)i * 2]     = o0;
        ((ushort4*)xb)[(size_t)i * 2 + 1] = o1;
        return;
    }
    const int wid = blockIdx.x >> 3;   // 0..6
    const int kb  = blockIdx.x & 7;
    const float* src;
    switch (wid) {
        case 0: src = w_in1; break;
        case 1: src = w_in2; break;
        case 2: src = w_e1; break;              // top half (send side)
        case 3: src = w_e1 + 65536; break;      // bottom half (recv side)
        case 4: src = w_e2; break;
        case 5: src = w_n1; break;
        default: src = w_n2; break;
    }
#pragma unroll
    for (int k0 = 0; k0 < 32; k0++)
        tile[k0][t] = f2bf(src[(size_t)(kb * 32 + k0) * 256 + t]);  // coalesced
    __syncthreads();
    ushort_t* base = dst + wid * 65536 + kb * 8192 + t * 32;
    const int sw = (t >> 1) & 3;
#pragma unroll
    for (int kc = 0; kc < 4; kc++) {
        union { uint4 q; ushort_t u[8]; } w;
#pragma unroll
        for (int ko = 0; ko < 8; ko++) w.u[ko] = tile[kc * 8 + ko][t];
        *(uint4*)&base[(kc ^ sw) * 8] = w.q;
    }
}

// ---------------------------------------------------------------------------
// Fused MLP chain (R10). Block = 32 rows, 4 waves (wave owns a 64-col slice).
// A-tiles [32][256] bf16 in LDS, XOR chunk swizzle: elem off =
//   r*256 + ((kc ^ (r&7))*8) + (k&7), kc = k>>3.
// Swapped MFMA: acc = mfma(Wfrag, Xfrag) -> lane holds 4 k-contiguous outputs.

__device__ __forceinline__ void layer_to_lds(
    const ushort_t* __restrict__ wimg, const float* __restrict__ bias,
    const ushort_t* __restrict__ As, ushort_t* __restrict__ Ad,
    const int w, const int lr, const int lg)
{
    int boffs[4]; float4 b4[4];
#pragma unroll
    for (int fn = 0; fn < 4; fn++) {
        const int n = w * 64 + fn * 16 + lr;
        boffs[fn] = n * 32 + ((lg ^ ((n >> 1) & 3)) * 8);
        b4[fn] = *(const float4*)&bias[w * 64 + fn * 16 + lg * 4];
    }
    bf16x8 bc[4];
#pragma unroll
    for (int fn = 0; fn < 4; fn++) bc[fn] = *(const bf16x8*)&wimg[boffs[fn]];
    f32x4 acc[4][2] = {};
#pragma unroll
    for (int kb = 0; kb < 8; kb++) {
        bf16x8 bn[4];
        if (kb < 7)
#pragma unroll
            for (int fn = 0; fn < 4; fn++)
                bn[fn] = *(const bf16x8*)&wimg[(kb + 1) * 8192 + boffs[fn]];
        bf16x8 af[2];
#pragma unroll
        for (int fm = 0; fm < 2; fm++) {
            const int r = fm * 16 + lr;
            af[fm] = *(const bf16x8*)&As[r * 256 + (((kb * 4 + lg) ^ (r & 7)) * 8)];
        }
#pragma unroll
        for (int fn = 0; fn < 4; fn++)
#pragma unroll
            for (int fm = 0; fm < 2; fm++)
                acc[fn][fm] = __builtin_amdgcn_mfma_f32_16x16x32_bf16(
                    bc[fn], af[fm], acc[fn][fm], 0, 0, 0);
        if (kb < 7)
#pragma unroll
            for (int fn = 0; fn < 4; fn++) bc[fn] = bn[fn];
    }
#pragma unroll
    for (int fn = 0; fn < 4; fn++) {
        const int k0 = w * 64 + fn * 16 + lg * 4;     // output col = next-layer k
        const int kc = k0 >> 3, kj = k0 & 7;
#pragma unroll
        for (int fm = 0; fm < 2; fm++) {
            const int m = fm * 16 + lr;
            float v0 = fmaxf(acc[fn][fm][0] + b4[fn].x, 0.f);
            float v1 = fmaxf(acc[fn][fm][1] + b4[fn].y, 0.f);
            float v2 = fmaxf(acc[fn][fm][2] + b4[fn].z, 0.f);
            float v3 = fmaxf(acc[fn][fm][3] + b4[fn].w, 0.f);
            uint2 q = { cvt_pk_bf16(v0, v1), cvt_pk_bf16(v2, v3) };
            *(uint2*)&Ad[m * 256 + ((kc ^ (m & 7)) * 8) + kj] = q;
        }
    }
}

__device__ __forceinline__ void layer_e1(
    const ushort_t* __restrict__ wE, const float* __restrict__ bE,
    const ushort_t* __restrict__ As, ushort_t* __restrict__ UVb,
    const int m0, const int w, const int lr, const int lg)
{
    const ushort_t* wimg = (w < 2) ? wE : (wE + 65536);
    const int nb = (w & 1) * 128;
    int boffs[8]; float4 b4[8];
#pragma unroll
    for (int fn = 0; fn < 8; fn++) {
        const int n = nb + fn * 16 + lr;
        boffs[fn] = n * 32 + ((lg ^ ((n >> 1) & 3)) * 8);
        if (w < 2) b4[fn] = *(const float4*)&bE[nb + fn * 16 + lg * 4];
        else       b4[fn] = make_float4(0.f, 0.f, 0.f, 0.f);
    }
    bf16x8 bc[8];
#pragma unroll
    for (int fn = 0; fn < 8; fn++) bc[fn] = *(const bf16x8*)&wimg[boffs[fn]];
    f32x4 acc[8][2] = {};
#pragma unroll
    for (int kb = 0; kb < 8; kb++) {
        bf16x8 bn[8];
        if (kb < 7)
#pragma unroll
            for (int fn = 0; fn < 8; fn++)
                bn[fn] = *(const bf16x8*)&wimg[(kb + 1) * 8192 + boffs[fn]];
        bf16x8 af[2];
#pragma unroll
        for (int fm = 0; fm < 2; fm++) {
            const int r = fm * 16 + lr;
            af[fm] = *(const bf16x8*)&As[r * 256 + (((kb * 4 + lg) ^ (r & 7)) * 8)];
        }
#pragma unroll
        for (int fn = 0; fn < 8; fn++)
#pragma unroll
            for (int fm = 0; fm < 2; fm++)
                acc[fn][fm] = __builtin_amdgcn_mfma_f32_16x16x32_bf16(
                    bc[fn], af[fm], acc[fn][fm], 0, 0, 0);
        if (kb < 7)
#pragma unroll
            for (int fn = 0; fn < 8; fn++) bc[fn] = bn[fn];
    }
#pragma unroll
    for (int fn = 0; fn < 8; fn++) {
        const int nglob = w * 128 + fn * 16 + lg * 4;
#pragma unroll
        for (int fm = 0; fm < 2; fm++) {
            const int node = m0 + fm * 16 + lr;
            float v0 = acc[fn][fm][0] + b4[fn].x;
            float v1 = acc[fn][fm][1] + b4[fn].y;
            float v2 = acc[fn][fm][2] + b4[fn].z;
            float v3 = acc[fn][fm][3] + b4[fn].w;
            uint2 q = { cvt_pk_bf16(v0, v1), cvt_pk_bf16(v2, v3) };
            *(uint2*)&UVb[(size_t)node * 512 + nglob] = q;
        }
    }
}

__device__ __forceinline__ void layer_fin(
    const ushort_t* __restrict__ wimg, const float* __restrict__ bias,
    const ushort_t* __restrict__ As, float* __restrict__ out,
    const int m0, const int w, const int lr, const int lg)
{
    int boffs[4]; float4 b4[4];
#pragma unroll
    for (int fn = 0; fn < 4; fn++) {
        const int n = w * 64 + fn * 16 + lr;
        boffs[fn] = n * 32 + ((lg ^ ((n >> 1) & 3)) * 8);
        b4[fn] = *(const float4*)&bias[w * 64 + fn * 16 + lg * 4];
    }
    bf16x8 bc[4];
#pragma unroll
    for (int fn = 0; fn < 4; fn++) bc[fn] = *(const bf16x8*)&wimg[boffs[fn]];
    f32x4 acc[4][2] = {};
#pragma unroll
    for (int kb = 0; kb < 8; kb++) {
        bf16x8 bn[4];
        if (kb < 7)
#pragma unroll
            for (int fn = 0; fn < 4; fn++)
                bn[fn] = *(const bf16x8*)&wimg[(kb + 1) * 8192 + boffs[fn]];
        bf16x8 af[2];
#pragma unroll
        for (int fm = 0; fm < 2; fm++) {
            const int r = fm * 16 + lr;
            af[fm] = *(const bf16x8*)&As[r * 256 + (((kb * 4 + lg) ^ (r & 7)) * 8)];
        }
#pragma unroll
        for (int fn = 0; fn < 4; fn++)
#pragma unroll
            for (int fm = 0; fm < 2; fm++)
                acc[fn][fm] = __builtin_amdgcn_mfma_f32_16x16x32_bf16(
                    bc[fn], af[fm], acc[fn][fm], 0, 0, 0);
        if (kb < 7)
#pragma unroll
            for (int fn = 0; fn < 4; fn++) bc[fn] = bn[fn];
    }
#pragma unroll
    for (int fn = 0; fn < 4; fn++) {
        const int col = w * 64 + fn * 16 + lg * 4;
#pragma unroll
        for (int fm = 0; fm < 2; fm++) {
            const int row = m0 + fm * 16 + lr;
            float4 o;
            o.x = fmaxf(acc[fn][fm][0] + b4[fn].x, 0.f);
            o.y = fmaxf(acc[fn][fm][1] + b4[fn].y, 0.f);
            o.z = fmaxf(acc[fn][fm][2] + b4[fn].z, 0.f);
            o.w = fmaxf(acc[fn][fm][3] + b4[fn].w, 0.f);
            *(float4*)&out[(size_t)row * 256 + col] = o;
        }
    }
}

template <int THREE>
__global__ __launch_bounds__(256, 2) void mlp_chain(
    const ushort_t* __restrict__ in,
    const ushort_t* __restrict__ wA, const float* __restrict__ bA,
    const ushort_t* __restrict__ wB, const float* __restrict__ bB,
    const ushort_t* __restrict__ wE, const float* __restrict__ bE,
    void* __restrict__ out)
{
    __shared__ ushort_t A0[32 * 256];
    __shared__ ushort_t A1[32 * 256];
    const int m0 = blockIdx.x * 32;
    const int t = threadIdx.x;
    const int lane = t & 63, w = t >> 6;
    const int lr = lane & 15, lg = lane >> 4;

#pragma unroll
    for (int i = 0; i < 4; i++) {
        const int r = i * 8 + (t >> 5);
        const int p = t & 31;
        gload16(in + (size_t)(m0 + r) * 256 + ((p ^ (r & 7)) * 8), &A0[i * 2048 + t * 8]);
    }
    __syncthreads();

    layer_to_lds(wA, bA, A0, A1, w, lr, lg);
    __syncthreads();
    if constexpr (THREE) {
        layer_to_lds(wB, bB, A1, A0, w, lr, lg);
        __syncthreads();
        layer_e1(wE, bE, A0, (ushort_t*)out, m0, w, lr, lg);
    } else {
        layer_fin(wB, bB, A1, (float*)out, m0, w, lr, lg);
    }
}

// ---------------------------------------------------------------------------
// Fused edge layer-2 + scatter-mean, v13: barrier-free, LDS-free.
// Grid 2048 x 256 thr (4 independent waves). Block = (batch, quad of 4
// receivers); wave w owns cols [w*64, w*64+64): wave tile 128x64, acc[8][4].
// Each lane builds its A-fragment relu(U'[si]+V[j]) directly in registers
// from per-lane global loads (UV is L2/L3-resident). B-frags from the
// swizzled w_e2 image, prefetched one K-step ahead. No LDS, no barriers.
__global__ __launch_bounds__(256, 2) void edge_fused(
    const ushort_t* __restrict__ UVb,   // [8192][512] bf16: U'(+b_e1) | V
    const ushort_t* __restrict__ WBsw,  // swizzled w_e2 image
    const float* __restrict__ b2,
    ushort_t* __restrict__ agg)         // [8192][256] bf16
{
    const int logical = (blockIdx.x & 7) * 256 + (blockIdx.x >> 3);  // 2048%8==0
    const int bb = logical >> 3;        // batch
    const int g0 = (logical & 7) * 4;   // first receiver of the quad
    const int t = threadIdx.x;
    const int lane = t & 63;
    const int w = t >> 6;
    const int lr = lane & 15, lg = lane >> 4;

    // per-lane u/v element offsets for the 8 m-fragments (rows m*16+lr)
    int uoff[8], voff[4];
#pragma unroll
    for (int h = 0; h < 4; h++) {
        const int j = g0 + h;
        voff[h] = (bb * 32 + j) * 512 + 256 + lg * 8;
#pragma unroll
        for (int q = 0; q < 2; q++) {
            const int s = q * 16 + lr;                      // slot 0..31
            const int si = (s == 31) ? j : (s + (s >= j ? 1 : 0));
            uoff[h * 2 + q] = (bb * 32 + si) * 512 + lg * 8;
        }
    }
    const int bbase = (w * 64 + lr) * 32 + ((lg ^ ((lr >> 1) & 3)) * 8);

    f32x4 acc[8][4] = {};
    bf16x8 bc[4];
#pragma unroll
    for (int fn = 0; fn < 4; fn++) bc[fn] = *(const bf16x8*)&WBsw[bbase + fn * 512];

    for (int kb = 0; kb < 8; kb++) {
        // prefetch next-step B (consumed next iteration)
        bf16x8 bn[4];
        if (kb < 7)
#pragma unroll
            for (int fn = 0; fn < 4; fn++)
                bn[fn] = *(const bf16x8*)&WBsw[(kb + 1) * 8192 + bbase + fn * 512];
        const int ko = kb * 32;
#pragma unroll
        for (int m = 0; m < 8; m++) {
            uint4 u = *(const uint4*)&UVb[uoff[m] + ko];
            uint4 v = *(const uint4*)&UVb[voff[m >> 1] + ko];   // CSE'd per pair
            union { uint4 q; bf16x8 b; } af;
            af.q.x = cvt_pk_bf16(fmaxf(lo16f(u.x) + lo16f(v.x), 0.f),
                                 fmaxf(hi16f(u.x) + hi16f(v.x), 0.f));
            af.q.y = cvt_pk_bf16(fmaxf(lo16f(u.y) + lo16f(v.y), 0.f),
                                 fmaxf(hi16f(u.y) + hi16f(v.y), 0.f));
            af.q.z = cvt_pk_bf16(fmaxf(lo16f(u.z) + lo16f(v.z), 0.f),
                                 fmaxf(hi16f(u.z) + hi16f(v.z), 0.f));
            af.q.w = cvt_pk_bf16(fmaxf(lo16f(u.w) + lo16f(v.w), 0.f),
                                 fmaxf(hi16f(u.w) + hi16f(v.w), 0.f));
#pragma unroll
            for (int fn = 0; fn < 4; fn++)
                acc[m][fn] = __builtin_amdgcn_mfma_f32_16x16x32_bf16(
                    af.b, bc[fn], acc[m][fn], 0, 0, 0);
        }
        if (kb < 7)
#pragma unroll
            for (int fn = 0; fn < 4; fn++) bc[fn] = bn[fn];
    }

    // ---- Epilogue: bias+relu, sum 31 real slots per receiver, /31, bf16 out.
#pragma unroll
    for (int fn = 0; fn < 4; fn++) {
        const int col = w * 64 + fn * 16 + lr;
        const float bvf = b2[col];
#pragma unroll
        for (int recv = 0; recv < 4; recv++) {
            float sum = 0.f;
#pragma unroll
            for (int q = 0; q < 2; q++) {
                const int fm = recv * 2 + q;
#pragma unroll
                for (int r = 0; r < 4; r++) {
                    float v = fmaxf(acc[fm][fn][r] + bvf, 0.f);
                    if (!(q == 1 && lg == 3 && r == 3)) sum += v;  // skip slot 31
                }
            }
            sum += __shfl_xor(sum, 16);
            sum += __shfl_xor(sum, 32);
            if (lane < 16)
                agg[(size_t)(bb * 32 + g0 + recv) * 256 + col] = f2bf(sum * (1.0f / 31.0f));
        }
    }
}

// ---------------------------------------------------------------------------
extern "C" void kernel_launch(void* const* d_in, const int* in_sizes, int n_in,
                              void* d_out, int out_size, void* d_ws, size_t ws_size,
                              hipStream_t stream)
{
    const float* x     = (const float*)d_in[0];
    const float* w_in1 = (const float*)d_in[3];
    const float* b_in1 = (const float*)d_in[4];
    const float* w_in2 = (const float*)d_in[5];
    const float* b_in2 = (const float*)d_in[6];
    const float* w_e1  = (const float*)d_in[7];
    const float* b_e1  = (const float*)d_in[8];
    const float* w_e2  = (const float*)d_in[9];
    const float* b_e2  = (const float*)d_in[10];
    const float* w_n1  = (const float*)d_in[11];
    const float* b_n1  = (const float*)d_in[12];
    const float* w_n2  = (const float*)d_in[13];
    const float* b_n2  = (const float*)d_in[14];

    char* ws = (char*)d_ws;
    size_t off = 0;
    auto alloc = [&](size_t n) { char* p = ws + off; off += (n + 255) & ~(size_t)255; return p; };

    ushort_t* wt  = (ushort_t*)alloc(7 * 65536 * sizeof(ushort_t));
    ushort_t* xb  = (ushort_t*)alloc(8192 * 256 * 2);
    ushort_t* UVb = (ushort_t*)alloc(8192 * 512 * 2);
    ushort_t* ag  = (ushort_t*)alloc(8192 * 256 * 2);
    (void)ws_size; (void)in_sizes; (void)n_in; (void)out_size;

    prep_all<<<1080, 256, 0, stream>>>(w_in1, w_in2, w_e1, w_e2, w_n1, w_n2, wt, x, xb);

    // pass 0 front: in1 -> in2 -> e1
    mlp_chain<1><<<256, 256, 0, stream>>>(xb,
        wt + 0 * 65536, b_in1, wt + 1 * 65536, b_in2, wt + 2 * 65536, b_e1, UVb);
    edge_fused<<<2048, 256, 0, stream>>>(UVb, wt + 4 * 65536, b_e2, ag);
    // pass 1 front: n1 -> n2 -> e1
    mlp_chain<1><<<256, 256, 0, stream>>>(ag,
        wt + 5 * 65536, b_n1, wt + 6 * 65536, b_n2, wt + 2 * 65536, b_e1, UVb);
    edge_fused<<<2048, 256, 0, stream>>>(UVb, wt + 4 * 65536, b_e2, ag);
    // final: n1 -> n2 (f32 out)
    mlp_chain<0><<<256, 256, 0, stream>>>(ag,
        wt + 5 * 65536, b_n1, wt + 6 * 65536, b_n2, nullptr, nullptr, d_out);
}

// Round 13
// 146.246 us; speedup vs baseline: 1.6325x; 1.6325x over previous
//
#include <hip/hip_runtime.h>

// GNN encoder, B=256, N=32, F=256, fully-connected edges, 2 passes.
// bf16 MFMA 16x16x32, fp32 accum.
// R13: edge v15 — N-split blocks (M128 x N128, grid 4096), wave 64x64
// (acc 64 regs), launch_bounds(256,3) for 3 waves/SIMD; raw s_barrier with
// lgkmcnt-only drain (prefetch loads stay in flight). MLP chains (R10),
// merged prep (R11) unchanged.

typedef short bf16x8 __attribute__((ext_vector_type(8)));
typedef float f32x4 __attribute__((ext_vector_type(4)));
typedef unsigned short ushort_t;

__device__ __forceinline__ unsigned short f2bf(float f) {
    unsigned u = __float_as_uint(f);
    u += 0x7fff + ((u >> 16) & 1);   // RNE
    return (unsigned short)(u >> 16);
}
__device__ __forceinline__ float lo16f(unsigned w) { return __uint_as_float(w << 16); }
__device__ __forceinline__ float hi16f(unsigned w) { return __uint_as_float(w & 0xffff0000u); }
__device__ __forceinline__ unsigned cvt_pk_bf16(float lo, float hi) {
    unsigned r;
    asm volatile("v_cvt_pk_bf16_f32 %0, %1, %2" : "=v"(r) : "v"(lo), "v"(hi));
    return r;
}
__device__ __forceinline__ void gload16(const void* g, void* l) {
    __builtin_amdgcn_global_load_lds(
        (const __attribute__((address_space(1))) void*)g,
        (__attribute__((address_space(3))) void*)l, 16, 0, 0);
}
__device__ __forceinline__ void soft_barrier() {
    // drain LDS ops only; keep global loads in flight across the barrier
    asm volatile("s_waitcnt lgkmcnt(0)" ::: "memory");
    __builtin_amdgcn_sched_barrier(0);
    __builtin_amdgcn_s_barrier();
}

// ---------------------------------------------------------------------------
// Weight prep (blocks 0..55) + x conversion (blocks 56..1079), merged.
// Weight image: idx = kq*8192 + n*32 + (kc ^ ((n>>1)&3))*8 + (k&7), kq=k>>5.
__global__ __launch_bounds__(256) void prep_all(
    const float* __restrict__ w_in1, const float* __restrict__ w_in2,
    const float* __restrict__ w_e1,  const float* __restrict__ w_e2,
    const float* __restrict__ w_n1,  const float* __restrict__ w_n2,
    ushort_t* __restrict__ dst,
    const float* __restrict__ x, ushort_t* __restrict__ xb)
{
    __shared__ ushort_t tile[32][264];
    const int t = threadIdx.x;
    if (blockIdx.x >= 56) {
        const int i = (blockIdx.x - 56) * 256 + t;
        const float4* p = (const float4*)x + (size_t)i * 2;
        float4 a = p[0], b = p[1];
        ushort4 o0 = make_ushort4(f2bf(a.x), f2bf(a.y), f2bf(a.z), f2bf(a.w));
        ushort4 o1 = make_ushort4(f2bf(b.x), f2bf(b.y), f2bf(b.z), f2bf(b.w));
        ((ushort4*)xb)[(size_t)i * 2]     = o0;
        ((ushort4*)xb)[(size_t)i * 2 + 1] = o1;
        return;
    }
    const int wid = blockIdx.x >> 3;   // 0..6
    const int kb  = blockIdx.x & 7;
    const float* src;
    switch (wid) {
        case 0: src = w_in1; break;
        case 1: src = w_in2; break;
        case 2: src = w_e1; break;              // top half (send side)
        case 3: src = w_e1 + 65536; break;      // bottom half (recv side)
        case 4: src = w_e2; break;
        case 5: src = w_n1; break;
        default: src = w_n2; break;
    }
#pragma unroll
    for (int k0 = 0; k0 < 32; k0++)
        tile[k0][t] = f2bf(src[(size_t)(kb * 32 + k0) * 256 + t]);  // coalesced
    __syncthreads();
    ushort_t* base = dst + wid * 65536 + kb * 8192 + t * 32;
    const int sw = (t >> 1) & 3;
#pragma unroll
    for (int kc = 0; kc < 4; kc++) {
        union { uint4 q; ushort_t u[8]; } w;
#pragma unroll
        for (int ko = 0; ko < 8; ko++) w.u[ko] = tile[kc * 8 + ko][t];
        *(uint4*)&base[(kc ^ sw) * 8] = w.q;
    }
}

// ---------------------------------------------------------------------------
// Fused MLP chain (R10). Block = 32 rows, 4 waves (wave owns a 64-col slice).
// A-tiles [32][256] bf16 in LDS, XOR chunk swizzle: elem off =
//   r*256 + ((kc ^ (r&7))*8) + (k&7), kc = k>>3.
// Swapped MFMA: acc = mfma(Wfrag, Xfrag) -> lane holds 4 k-contiguous outputs.

__device__ __forceinline__ void layer_to_lds(
    const ushort_t* __restrict__ wimg, const float* __restrict__ bias,
    const ushort_t* __restrict__ As, ushort_t* __restrict__ Ad,
    const int w, const int lr, const int lg)
{
    int boffs[4]; float4 b4[4];
#pragma unroll
    for (int fn = 0; fn < 4; fn++) {
        const int n = w * 64 + fn * 16 + lr;
        boffs[fn] = n * 32 + ((lg ^ ((n >> 1) & 3)) * 8);
        b4[fn] = *(const float4*)&bias[w * 64 + fn * 16 + lg * 4];
    }
    bf16x8 bc[4];
#pragma unroll
    for (int fn = 0; fn < 4; fn++) bc[fn] = *(const bf16x8*)&wimg[boffs[fn]];
    f32x4 acc[4][2] = {};
#pragma unroll
    for (int kb = 0; kb < 8; kb++) {
        bf16x8 bn[4];
        if (kb < 7)
#pragma unroll
            for (int fn = 0; fn < 4; fn++)
                bn[fn] = *(const bf16x8*)&wimg[(kb + 1) * 8192 + boffs[fn]];
        bf16x8 af[2];
#pragma unroll
        for (int fm = 0; fm < 2; fm++) {
            const int r = fm * 16 + lr;
            af[fm] = *(const bf16x8*)&As[r * 256 + (((kb * 4 + lg) ^ (r & 7)) * 8)];
        }
#pragma unroll
        for (int fn = 0; fn < 4; fn++)
#pragma unroll
            for (int fm = 0; fm < 2; fm++)
                acc[fn][fm] = __builtin_amdgcn_mfma_f32_16x16x32_bf16(
                    bc[fn], af[fm], acc[fn][fm], 0, 0, 0);
        if (kb < 7)
#pragma unroll
            for (int fn = 0; fn < 4; fn++) bc[fn] = bn[fn];
    }
#pragma unroll
    for (int fn = 0; fn < 4; fn++) {
        const int k0 = w * 64 + fn * 16 + lg * 4;     // output col = next-layer k
        const int kc = k0 >> 3, kj = k0 & 7;
#pragma unroll
        for (int fm = 0; fm < 2; fm++) {
            const int m = fm * 16 + lr;
            float v0 = fmaxf(acc[fn][fm][0] + b4[fn].x, 0.f);
            float v1 = fmaxf(acc[fn][fm][1] + b4[fn].y, 0.f);
            float v2 = fmaxf(acc[fn][fm][2] + b4[fn].z, 0.f);
            float v3 = fmaxf(acc[fn][fm][3] + b4[fn].w, 0.f);
            uint2 q = { cvt_pk_bf16(v0, v1), cvt_pk_bf16(v2, v3) };
            *(uint2*)&Ad[m * 256 + ((kc ^ (m & 7)) * 8) + kj] = q;
        }
    }
}

__device__ __forceinline__ void layer_e1(
    const ushort_t* __restrict__ wE, const float* __restrict__ bE,
    const ushort_t* __restrict__ As, ushort_t* __restrict__ UVb,
    const int m0, const int w, const int lr, const int lg)
{
    const ushort_t* wimg = (w < 2) ? wE : (wE + 65536);
    const int nb = (w & 1) * 128;
    int boffs[8]; float4 b4[8];
#pragma unroll
    for (int fn = 0; fn < 8; fn++) {
        const int n = nb + fn * 16 + lr;
        boffs[fn] = n * 32 + ((lg ^ ((n >> 1) & 3)) * 8);
        if (w < 2) b4[fn] = *(const float4*)&bE[nb + fn * 16 + lg * 4];
        else       b4[fn] = make_float4(0.f, 0.f, 0.f, 0.f);
    }
    bf16x8 bc[8];
#pragma unroll
    for (int fn = 0; fn < 8; fn++) bc[fn] = *(const bf16x8*)&wimg[boffs[fn]];
    f32x4 acc[8][2] = {};
#pragma unroll
    for (int kb = 0; kb < 8; kb++) {
        bf16x8 bn[8];
        if (kb < 7)
#pragma unroll
            for (int fn = 0; fn < 8; fn++)
                bn[fn] = *(const bf16x8*)&wimg[(kb + 1) * 8192 + boffs[fn]];
        bf16x8 af[2];
#pragma unroll
        for (int fm = 0; fm < 2; fm++) {
            const int r = fm * 16 + lr;
            af[fm] = *(const bf16x8*)&As[r * 256 + (((kb * 4 + lg) ^ (r & 7)) * 8)];
        }
#pragma unroll
        for (int fn = 0; fn < 8; fn++)
#pragma unroll
            for (int fm = 0; fm < 2; fm++)
                acc[fn][fm] = __builtin_amdgcn_mfma_f32_16x16x32_bf16(
                    bc[fn], af[fm], acc[fn][fm], 0, 0, 0);
        if (kb < 7)
#pragma unroll
            for (int fn = 0; fn < 8; fn++) bc[fn] = bn[fn];
    }
#pragma unroll
    for (int fn = 0; fn < 8; fn++) {
        const int nglob = w * 128 + fn * 16 + lg * 4;
#pragma unroll
        for (int fm = 0; fm < 2; fm++) {
            const int node = m0 + fm * 16 + lr;
            float v0 = acc[fn][fm][0] + b4[fn].x;
            float v1 = acc[fn][fm][1] + b4[fn].y;
            float v2 = acc[fn][fm][2] + b4[fn].z;
            float v3 = acc[fn][fm][3] + b4[fn].w;
            uint2 q = { cvt_pk_bf16(v0, v1), cvt_pk_bf16(v2, v3) };
            *(uint2*)&UVb[(size_t)node * 512 + nglob] = q;
        }
    }
}

__device__ __forceinline__ void layer_fin(
    const ushort_t* __restrict__ wimg, const float* __restrict__ bias,
    const ushort_t* __restrict__ As, float* __restrict__ out,
    const int m0, const int w, const int lr, const int lg)
{
    int boffs[4]; float4 b4[4];
#pragma unroll
    for (int fn = 0; fn < 4; fn++) {
        const int n = w * 64 + fn * 16 + lr;
        boffs[fn] = n * 32 + ((lg ^ ((n >> 1) & 3)) * 8);
        b4[fn] = *(const float4*)&bias[w * 64 + fn * 16 + lg * 4];
    }
    bf16x8 bc[4];
#pragma unroll
    for (int fn = 0; fn < 4; fn++) bc[fn] = *(const bf16x8*)&wimg[boffs[fn]];
    f32x4 acc[4][2] = {};
#pragma unroll
    for (int kb = 0; kb < 8; kb++) {
        bf16x8 bn[4];
        if (kb < 7)
#pragma unroll
            for (int fn = 0; fn < 4; fn++)
                bn[fn] = *(const bf16x8*)&wimg[(kb + 1) * 8192 + boffs[fn]];
        bf16x8 af[2];
#pragma unroll
        for (int fm = 0; fm < 2; fm++) {
            const int r = fm * 16 + lr;
            af[fm] = *(const bf16x8*)&As[r * 256 + (((kb * 4 + lg) ^ (r & 7)) * 8)];
        }
#pragma unroll
        for (int fn = 0; fn < 4; fn++)
#pragma unroll
            for (int fm = 0; fm < 2; fm++)
                acc[fn][fm] = __builtin_amdgcn_mfma_f32_16x16x32_bf16(
                    bc[fn], af[fm], acc[fn][fm], 0, 0, 0);
        if (kb < 7)
#pragma unroll
            for (int fn = 0; fn < 4; fn++) bc[fn] = bn[fn];
    }
#pragma unroll
    for (int fn = 0; fn < 4; fn++) {
        const int col = w * 64 + fn * 16 + lg * 4;
#pragma unroll
        for (int fm = 0; fm < 2; fm++) {
            const int row = m0 + fm * 16 + lr;
            float4 o;
            o.x = fmaxf(acc[fn][fm][0] + b4[fn].x, 0.f);
            o.y = fmaxf(acc[fn][fm][1] + b4[fn].y, 0.f);
            o.z = fmaxf(acc[fn][fm][2] + b4[fn].z, 0.f);
            o.w = fmaxf(acc[fn][fm][3] + b4[fn].w, 0.f);
            *(float4*)&out[(size_t)row * 256 + col] = o;
        }
    }
}

template <int THREE>
__global__ __launch_bounds__(256, 2) void mlp_chain(
    const ushort_t* __restrict__ in,
    const ushort_t* __restrict__ wA, const float* __restrict__ bA,
    const ushort_t* __restrict__ wB, const float* __restrict__ bB,
    const ushort_t* __restrict__ wE, const float* __restrict__ bE,
    void* __restrict__ out)
{
    __shared__ ushort_t A0[32 * 256];
    __shared__ ushort_t A1[32 * 256];
    const int m0 = blockIdx.x * 32;
    const int t = threadIdx.x;
    const int lane = t & 63, w = t >> 6;
    const int lr = lane & 15, lg = lane >> 4;

#pragma unroll
    for (int i = 0; i < 4; i++) {
        const int r = i * 8 + (t >> 5);
        const int p = t & 31;
        gload16(in + (size_t)(m0 + r) * 256 + ((p ^ (r & 7)) * 8), &A0[i * 2048 + t * 8]);
    }
    __syncthreads();

    layer_to_lds(wA, bA, A0, A1, w, lr, lg);
    __syncthreads();
    if constexpr (THREE) {
        layer_to_lds(wB, bB, A1, A0, w, lr, lg);
        __syncthreads();
        layer_e1(wE, bE, A0, (ushort_t*)out, m0, w, lr, lg);
    } else {
        layer_fin(wB, bB, A1, (float*)out, m0, w, lr, lg);
    }
}

// ---------------------------------------------------------------------------
// Fused edge layer-2 + scatter-mean, v15: N-split for occupancy.
// Grid 4096 = 2048 M-units x 2 N-halves. Block: 128 virtual rows (4 recv x
// 32 slots, slot31 dummy) x 128 cols. 4 waves 2m x 2n, wave tile 64x64
// (acc[4][4] = 64 regs). A built into BK=64 LDS dbuf (as v10); B-frags from
// the L2-resident swizzled image (loaded post-streak, as v10). Raw barrier
// drains lgkm only — global prefetch stays in flight. 3 waves/SIMD target.
__global__ __launch_bounds__(256, 3) void edge_fused(
    const ushort_t* __restrict__ UVb,   // [8192][512] bf16: U'(+b_e1) | V
    const ushort_t* __restrict__ WBsw,  // swizzled w_e2 image
    const float* __restrict__ b2,
    ushort_t* __restrict__ agg)         // [8192][256] bf16
{
    __shared__ ushort_t As[2][128 * 64];   // 16KB each

    const int logical = (blockIdx.x & 7) * 512 + (blockIdx.x >> 3);  // 4096%8==0
    const int unit = logical >> 1;       // M-unit (batch, quad)
    const int nh = logical & 1;          // N half
    const int bb = unit >> 3;            // batch
    const int g0 = (unit & 7) * 4;       // first receiver of the quad
    const int t = threadIdx.x;
    const int lane = t & 63;
    const int w = t >> 6;
    const int wm = w >> 1, wn = w & 1;
    const int lr = lane & 15, lg = lane >> 4;

    // ---- A-build mapping (v10): 2 threads/row, 4 chunks (32 elems) each
    const int brow = t >> 1;            // 0..127
    const int kh = t & 1;               // which 32-k half of the 64-k tile
    const int jr = brow >> 5;
    const int s = brow & 31;
    const int j = g0 + jr;
    const int si = (s == 31) ? j : (s + (s >= j ? 1 : 0));
    const ushort_t* up = UVb + (size_t)(bb * 32 + si) * 512 + kh * 32;
    const ushort_t* vp = UVb + (size_t)(bb * 32 + j) * 512 + 256 + kh * 32;
    const int rs7 = brow & 7;
    int aw[4];
#pragma unroll
    for (int i = 0; i < 4; i++)
        aw[i] = brow * 64 + (((kh * 4 + i) ^ rs7) * 8);

    // ---- MFMA-side offsets: rows wm*64 + f*16 + lr, cols nh*128 + wn*64 + ...
    int aoff[4];
#pragma unroll
    for (int f = 0; f < 4; f++) {
        const int r = wm * 64 + f * 16 + lr;
        aoff[f] = r * 64 + ((lg ^ (r & 7)) * 8);
    }
    int boff[4];
#pragma unroll
    for (int fn = 0; fn < 4; fn++) {
        const int n = nh * 128 + wn * 64 + fn * 16 + lr;
        boff[fn] = n * 32 + ((lg ^ ((n >> 1) & 3)) * 8);
    }

    auto build = [&](int buf, const uint4* u, const uint4* v) {
#pragma unroll
        for (int i = 0; i < 4; i++) {
            uint4 q;
            q.x = cvt_pk_bf16(fmaxf(lo16f(u[i].x) + lo16f(v[i].x), 0.f),
                              fmaxf(hi16f(u[i].x) + hi16f(v[i].x), 0.f));
            q.y = cvt_pk_bf16(fmaxf(lo16f(u[i].y) + lo16f(v[i].y), 0.f),
                              fmaxf(hi16f(u[i].y) + hi16f(v[i].y), 0.f));
            q.z = cvt_pk_bf16(fmaxf(lo16f(u[i].z) + lo16f(v[i].z), 0.f),
                              fmaxf(hi16f(u[i].z) + hi16f(v[i].z), 0.f));
            q.w = cvt_pk_bf16(fmaxf(lo16f(u[i].w) + lo16f(v[i].w), 0.f),
                              fmaxf(hi16f(u[i].w) + hi16f(v[i].w), 0.f));
            *(uint4*)&As[buf][aw[i]] = q;
        }
    };

    // ---- prologue: build tile 0, load B for step 0
    {
        uint4 u[4], v[4];
#pragma unroll
        for (int i = 0; i < 4; i++) {
            u[i] = *(const uint4*)(up + i * 8);
            v[i] = *(const uint4*)(vp + i * 8);
        }
        build(0, u, v);
    }
    bf16x8 bc[2][4];
#pragma unroll
    for (int ks = 0; ks < 2; ks++)
#pragma unroll
        for (int fn = 0; fn < 4; fn++)
            bc[ks][fn] = *(const bf16x8*)&WBsw[ks * 8192 + boff[fn]];

    f32x4 acc[4][4] = {};

#pragma unroll
    for (int kb = 0; kb < 4; kb++) {
        const int cur = kb & 1;
        soft_barrier();                   // As[cur] built; lgkm drained only
        // issue u/v loads for next build (arrive under the MFMA streak)
        uint4 u[4], v[4];
        if (kb < 3) {
            const ushort_t* upn = up + (kb + 1) * 64;
            const ushort_t* vpn = vp + (kb + 1) * 64;
#pragma unroll
            for (int i = 0; i < 4; i++) {
                u[i] = *(const uint4*)(upn + i * 8);
                v[i] = *(const uint4*)(vpn + i * 8);
            }
        }
        // ---- 32-MFMA streak
        __builtin_amdgcn_s_setprio(1);
#pragma unroll
        for (int ks = 0; ks < 2; ks++) {
            bf16x8 af[4];
#pragma unroll
            for (int m = 0; m < 4; m++)
                af[m] = *(const bf16x8*)&As[cur][aoff[m] ^ (ks * 32)];
#pragma unroll
            for (int fn = 0; fn < 4; fn++)
#pragma unroll
                for (int m = 0; m < 4; m++)
                    acc[m][fn] = __builtin_amdgcn_mfma_f32_16x16x32_bf16(
                        af[m], bc[ks][fn], acc[m][fn], 0, 0, 0);
        }
        __builtin_amdgcn_s_setprio(0);
        if (kb < 3) {
            // next-step B loads (latency covered by build + next barrier)
#pragma unroll
            for (int ks = 0; ks < 2; ks++)
#pragma unroll
                for (int fn = 0; fn < 4; fn++)
                    bc[ks][fn] = *(const bf16x8*)&WBsw[((kb + 1) * 2 + ks) * 8192
                                                       + boff[fn]];
            build(cur ^ 1, u, v);         // u/v arrived under the streak
        }
    }

    // ---- Epilogue: bias+relu, sum 31 real slots per receiver, /31, bf16 out.
#pragma unroll
    for (int fn = 0; fn < 4; fn++) {
        const int col = nh * 128 + wn * 64 + fn * 16 + lr;
        const float bvf = b2[col];
#pragma unroll
        for (int h = 0; h < 2; h++) {     // receiver within wave's 64 rows
            float sum = 0.f;
#pragma unroll
            for (int q = 0; q < 2; q++) {
                const int f = 2 * h + q;
#pragma unroll
                for (int r = 0; r < 4; r++) {
                    float v = fmaxf(acc[f][fn][r] + bvf, 0.f);
                    if (!(q == 1 && lg == 3 && r == 3)) sum += v;  // skip slot 31
                }
            }
            sum += __shfl_xor(sum, 16);
            sum += __shfl_xor(sum, 32);
            if (lane < 16)
                agg[(size_t)(bb * 32 + g0 + wm * 2 + h) * 256 + col] =
                    f2bf(sum * (1.0f / 31.0f));
        }
    }
}

// ---------------------------------------------------------------------------
extern "C" void kernel_launch(void* const* d_in, const int* in_sizes, int n_in,
                              void* d_out, int out_size, void* d_ws, size_t ws_size,
                              hipStream_t stream)
{
    const float* x     = (const float*)d_in[0];
    const float* w_in1 = (const float*)d_in[3];
    const float* b_in1 = (const float*)d_in[4];
    const float* w_in2 = (const float*)d_in[5];
    const float* b_in2 = (const float*)d_in[6];
    const float* w_e1  = (const float*)d_in[7];
    const float* b_e1  = (const float*)d_in[8];
    const float* w_e2  = (const float*)d_in[9];
    const float* b_e2  = (const float*)d_in[10];
    const float* w_n1  = (const float*)d_in[11];
    const float* b_n1  = (const float*)d_in[12];
    const float* w_n2  = (const float*)d_in[13];
    const float* b_n2  = (const float*)d_in[14];

    char* ws = (char*)d_ws;
    size_t off = 0;
    auto alloc = [&](size_t n) { char* p = ws + off; off += (n + 255) & ~(size_t)255; return p; };

    ushort_t* wt  = (ushort_t*)alloc(7 * 65536 * sizeof(ushort_t));
    ushort_t* xb  = (ushort_t*)alloc(8192 * 256 * 2);
    ushort_t* UVb = (ushort_t*)alloc(8192 * 512 * 2);
    ushort_t* ag  = (ushort_t*)alloc(8192 * 256 * 2);
    (void)ws_size; (void)in_sizes; (void)n_in; (void)out_size;

    prep_all<<<1080, 256, 0, stream>>>(w_in1, w_in2, w_e1, w_e2, w_n1, w_n2, wt, x, xb);

    // pass 0 front: in1 -> in2 -> e1
    mlp_chain<1><<<256, 256, 0, stream>>>(xb,
        wt + 0 * 65536, b_in1, wt + 1 * 65536, b_in2, wt + 2 * 65536, b_e1, UVb);
    edge_fused<<<4096, 256, 0, stream>>>(UVb, wt + 4 * 65536, b_e2, ag);
    // pass 1 front: n1 -> n2 -> e1
    mlp_chain<1><<<256, 256, 0, stream>>>(ag,
        wt + 5 * 65536, b_n1, wt + 6 * 65536, b_n2, wt + 2 * 65536, b_e1, UVb);
    edge_fused<<<4096, 256, 0, stream>>>(UVb, wt + 4 * 65536, b_e2, ag);
    // final: n1 -> n2 (f32 out)
    mlp_chain<0><<<256, 256, 0, stream>>>(ag,
        wt + 5 * 65536, b_n1, wt + 6 * 65536, b_n2, nullptr, nullptr, d_out);
}

// Round 14
// 134.105 us; speedup vs baseline: 1.7803x; 1.0905x over previous
//
#include <hip/hip_runtime.h>

// GNN encoder, B=256, N=32, F=256, fully-connected edges, 2 passes.
// bf16 MFMA 16x16x32, fp32 accum.
// R14 = R10 base (best: 134.2us) + two targeted fixes:
//  - edge v10: lgkm-only soft barrier (post-streak B/u/v prefetch stays in
//    flight across the barrier; no vmcnt(0) drain).
//  - mlp_chain: depth-2 B prefetch (2 L2 chains in flight; covers latency at
//    1 wave/SIMD); e1 layer split into 2x 4-frag groups to fit registers.

typedef short bf16x8 __attribute__((ext_vector_type(8)));
typedef float f32x4 __attribute__((ext_vector_type(4)));
typedef unsigned short ushort_t;

__device__ __forceinline__ unsigned short f2bf(float f) {
    unsigned u = __float_as_uint(f);
    u += 0x7fff + ((u >> 16) & 1);   // RNE
    return (unsigned short)(u >> 16);
}
__device__ __forceinline__ float lo16f(unsigned w) { return __uint_as_float(w << 16); }
__device__ __forceinline__ float hi16f(unsigned w) { return __uint_as_float(w & 0xffff0000u); }
__device__ __forceinline__ unsigned cvt_pk_bf16(float lo, float hi) {
    unsigned r;
    asm volatile("v_cvt_pk_bf16_f32 %0, %1, %2" : "=v"(r) : "v"(lo), "v"(hi));
    return r;
}
__device__ __forceinline__ void gload16(const void* g, void* l) {
    __builtin_amdgcn_global_load_lds(
        (const __attribute__((address_space(1))) void*)g,
        (__attribute__((address_space(3))) void*)l, 16, 0, 0);
}
__device__ __forceinline__ void soft_barrier() {
    // drain LDS ops only; keep global loads in flight across the barrier
    asm volatile("s_waitcnt lgkmcnt(0)" ::: "memory");
    __builtin_amdgcn_sched_barrier(0);
    __builtin_amdgcn_s_barrier();
}

// ---------------------------------------------------------------------------
// Weight prep (blocks 0..55) + x conversion (blocks 56..1079), merged.
// Weight image: idx = kq*8192 + n*32 + (kc ^ ((n>>1)&3))*8 + (k&7), kq=k>>5.
__global__ __launch_bounds__(256) void prep_all(
    const float* __restrict__ w_in1, const float* __restrict__ w_in2,
    const float* __restrict__ w_e1,  const float* __restrict__ w_e2,
    const float* __restrict__ w_n1,  const float* __restrict__ w_n2,
    ushort_t* __restrict__ dst,
    const float* __restrict__ x, ushort_t* __restrict__ xb)
{
    __shared__ ushort_t tile[32][264];
    const int t = threadIdx.x;
    if (blockIdx.x >= 56) {
        const int i = (blockIdx.x - 56) * 256 + t;
        const float4* p = (const float4*)x + (size_t)i * 2;
        float4 a = p[0], b = p[1];
        ushort4 o0 = make_ushort4(f2bf(a.x), f2bf(a.y), f2bf(a.z), f2bf(a.w));
        ushort4 o1 = make_ushort4(f2bf(b.x), f2bf(b.y), f2bf(b.z), f2bf(b.w));
        ((ushort4*)xb)[(size_t)i * 2]     = o0;
        ((ushort4*)xb)[(size_t)i * 2 + 1] = o1;
        return;
    }
    const int wid = blockIdx.x >> 3;   // 0..6
    const int kb  = blockIdx.x & 7;
    const float* src;
    switch (wid) {
        case 0: src = w_in1; break;
        case 1: src = w_in2; break;
        case 2: src = w_e1; break;              // top half (send side)
        case 3: src = w_e1 + 65536; break;      // bottom half (recv side)
        case 4: src = w_e2; break;
        case 5: src = w_n1; break;
        default: src = w_n2; break;
    }
#pragma unroll
    for (int k0 = 0; k0 < 32; k0++)
        tile[k0][t] = f2bf(src[(size_t)(kb * 32 + k0) * 256 + t]);  // coalesced
    __syncthreads();
    ushort_t* base = dst + wid * 65536 + kb * 8192 + t * 32;
    const int sw = (t >> 1) & 3;
#pragma unroll
    for (int kc = 0; kc < 4; kc++) {
        union { uint4 q; ushort_t u[8]; } w;
#pragma unroll
        for (int ko = 0; ko < 8; ko++) w.u[ko] = tile[kc * 8 + ko][t];
        *(uint4*)&base[(kc ^ sw) * 8] = w.q;
    }
}

// ---------------------------------------------------------------------------
// Fused MLP chain. Block = 32 rows, 4 waves (wave owns a 64-col slice).
// A-tiles [32][256] bf16 in LDS, XOR chunk swizzle: elem off =
//   r*256 + ((kc ^ (r&7))*8) + (k&7), kc = k>>3.
// Swapped MFMA: acc = mfma(Wfrag, Xfrag) -> lane holds 4 k-contiguous outputs.
// B prefetch depth 2 (bq[3][4] rolling, statically indexed via full unroll).

__device__ __forceinline__ void layer_to_lds(
    const ushort_t* __restrict__ wimg, const float* __restrict__ bias,
    const ushort_t* __restrict__ As, ushort_t* __restrict__ Ad,
    const int w, const int lr, const int lg)
{
    int boffs[4]; float4 b4[4];
#pragma unroll
    for (int fn = 0; fn < 4; fn++) {
        const int n = w * 64 + fn * 16 + lr;
        boffs[fn] = n * 32 + ((lg ^ ((n >> 1) & 3)) * 8);
        b4[fn] = *(const float4*)&bias[w * 64 + fn * 16 + lg * 4];
    }
    bf16x8 bq[3][4];
#pragma unroll
    for (int fn = 0; fn < 4; fn++) bq[0][fn] = *(const bf16x8*)&wimg[boffs[fn]];
#pragma unroll
    for (int fn = 0; fn < 4; fn++) bq[1][fn] = *(const bf16x8*)&wimg[8192 + boffs[fn]];
    f32x4 acc[4][2] = {};
#pragma unroll
    for (int kb = 0; kb < 8; kb++) {
        if (kb < 6)
#pragma unroll
            for (int fn = 0; fn < 4; fn++)
                bq[(kb + 2) % 3][fn] = *(const bf16x8*)&wimg[(kb + 2) * 8192 + boffs[fn]];
        bf16x8 af[2];
#pragma unroll
        for (int fm = 0; fm < 2; fm++) {
            const int r = fm * 16 + lr;
            af[fm] = *(const bf16x8*)&As[r * 256 + (((kb * 4 + lg) ^ (r & 7)) * 8)];
        }
#pragma unroll
        for (int fn = 0; fn < 4; fn++)
#pragma unroll
            for (int fm = 0; fm < 2; fm++)
                acc[fn][fm] = __builtin_amdgcn_mfma_f32_16x16x32_bf16(
                    bq[kb % 3][fn], af[fm], acc[fn][fm], 0, 0, 0);
    }
#pragma unroll
    for (int fn = 0; fn < 4; fn++) {
        const int k0 = w * 64 + fn * 16 + lg * 4;     // output col = next-layer k
        const int kc = k0 >> 3, kj = k0 & 7;
#pragma unroll
        for (int fm = 0; fm < 2; fm++) {
            const int m = fm * 16 + lr;
            float v0 = fmaxf(acc[fn][fm][0] + b4[fn].x, 0.f);
            float v1 = fmaxf(acc[fn][fm][1] + b4[fn].y, 0.f);
            float v2 = fmaxf(acc[fn][fm][2] + b4[fn].z, 0.f);
            float v3 = fmaxf(acc[fn][fm][3] + b4[fn].w, 0.f);
            uint2 q = { cvt_pk_bf16(v0, v1), cvt_pk_bf16(v2, v3) };
            *(uint2*)&Ad[m * 256 + ((kc ^ (m & 7)) * 8) + kj] = q;
        }
    }
}

// e1: two sequential 4-frag groups (each depth-2), wave w covers 128 cols of
// [U'|V]: wimg selects top/bottom half of w_e1, nb = (w&1)*128 + g*64.
__device__ __forceinline__ void layer_e1(
    const ushort_t* __restrict__ wE, const float* __restrict__ bE,
    const ushort_t* __restrict__ As, ushort_t* __restrict__ UVb,
    const int m0, const int w, const int lr, const int lg)
{
    const ushort_t* wimg = (w < 2) ? wE : (wE + 65536);
#pragma unroll
    for (int g = 0; g < 2; g++) {
        const int nb = (w & 1) * 128 + g * 64;
        int boffs[4]; float4 b4[4];
#pragma unroll
        for (int fn = 0; fn < 4; fn++) {
            const int n = nb + fn * 16 + lr;
            boffs[fn] = n * 32 + ((lg ^ ((n >> 1) & 3)) * 8);
            if (w < 2) b4[fn] = *(const float4*)&bE[nb + fn * 16 + lg * 4];
            else       b4[fn] = make_float4(0.f, 0.f, 0.f, 0.f);
        }
        bf16x8 bq[3][4];
#pragma unroll
        for (int fn = 0; fn < 4; fn++) bq[0][fn] = *(const bf16x8*)&wimg[boffs[fn]];
#pragma unroll
        for (int fn = 0; fn < 4; fn++) bq[1][fn] = *(const bf16x8*)&wimg[8192 + boffs[fn]];
        f32x4 acc[4][2] = {};
#pragma unroll
        for (int kb = 0; kb < 8; kb++) {
            if (kb < 6)
#pragma unroll
                for (int fn = 0; fn < 4; fn++)
                    bq[(kb + 2) % 3][fn] = *(const bf16x8*)&wimg[(kb + 2) * 8192 + boffs[fn]];
            bf16x8 af[2];
#pragma unroll
            for (int fm = 0; fm < 2; fm++) {
                const int r = fm * 16 + lr;
                af[fm] = *(const bf16x8*)&As[r * 256 + (((kb * 4 + lg) ^ (r & 7)) * 8)];
            }
#pragma unroll
            for (int fn = 0; fn < 4; fn++)
#pragma unroll
                for (int fm = 0; fm < 2; fm++)
                    acc[fn][fm] = __builtin_amdgcn_mfma_f32_16x16x32_bf16(
                        bq[kb % 3][fn], af[fm], acc[fn][fm], 0, 0, 0);
        }
#pragma unroll
        for (int fn = 0; fn < 4; fn++) {
            const int nglob = w * 128 + g * 64 + fn * 16 + lg * 4;
#pragma unroll
            for (int fm = 0; fm < 2; fm++) {
                const int node = m0 + fm * 16 + lr;
                float v0 = acc[fn][fm][0] + b4[fn].x;
                float v1 = acc[fn][fm][1] + b4[fn].y;
                float v2 = acc[fn][fm][2] + b4[fn].z;
                float v3 = acc[fn][fm][3] + b4[fn].w;
                uint2 q = { cvt_pk_bf16(v0, v1), cvt_pk_bf16(v2, v3) };
                *(uint2*)&UVb[(size_t)node * 512 + nglob] = q;
            }
        }
    }
}

__device__ __forceinline__ void layer_fin(
    const ushort_t* __restrict__ wimg, const float* __restrict__ bias,
    const ushort_t* __restrict__ As, float* __restrict__ out,
    const int m0, const int w, const int lr, const int lg)
{
    int boffs[4]; float4 b4[4];
#pragma unroll
    for (int fn = 0; fn < 4; fn++) {
        const int n = w * 64 + fn * 16 + lr;
        boffs[fn] = n * 32 + ((lg ^ ((n >> 1) & 3)) * 8);
        b4[fn] = *(const float4*)&bias[w * 64 + fn * 16 + lg * 4];
    }
    bf16x8 bq[3][4];
#pragma unroll
    for (int fn = 0; fn < 4; fn++) bq[0][fn] = *(const bf16x8*)&wimg[boffs[fn]];
#pragma unroll
    for (int fn = 0; fn < 4; fn++) bq[1][fn] = *(const bf16x8*)&wimg[8192 + boffs[fn]];
    f32x4 acc[4][2] = {};
#pragma unroll
    for (int kb = 0; kb < 8; kb++) {
        if (kb < 6)
#pragma unroll
            for (int fn = 0; fn < 4; fn++)
                bq[(kb + 2) % 3][fn] = *(const bf16x8*)&wimg[(kb + 2) * 8192 + boffs[fn]];
        bf16x8 af[2];
#pragma unroll
        for (int fm = 0; fm < 2; fm++) {
            const int r = fm * 16 + lr;
            af[fm] = *(const bf16x8*)&As[r * 256 + (((kb * 4 + lg) ^ (r & 7)) * 8)];
        }
#pragma unroll
        for (int fn = 0; fn < 4; fn++)
#pragma unroll
            for (int fm = 0; fm < 2; fm++)
                acc[fn][fm] = __builtin_amdgcn_mfma_f32_16x16x32_bf16(
                    bq[kb % 3][fn], af[fm], acc[fn][fm], 0, 0, 0);
    }
#pragma unroll
    for (int fn = 0; fn < 4; fn++) {
        const int col = w * 64 + fn * 16 + lg * 4;
#pragma unroll
        for (int fm = 0; fm < 2; fm++) {
            const int row = m0 + fm * 16 + lr;
            float4 o;
            o.x = fmaxf(acc[fn][fm][0] + b4[fn].x, 0.f);
            o.y = fmaxf(acc[fn][fm][1] + b4[fn].y, 0.f);
            o.z = fmaxf(acc[fn][fm][2] + b4[fn].z, 0.f);
            o.w = fmaxf(acc[fn][fm][3] + b4[fn].w, 0.f);
            *(float4*)&out[(size_t)row * 256 + col] = o;
        }
    }
}

template <int THREE>
__global__ __launch_bounds__(256, 2) void mlp_chain(
    const ushort_t* __restrict__ in,
    const ushort_t* __restrict__ wA, const float* __restrict__ bA,
    const ushort_t* __restrict__ wB, const float* __restrict__ bB,
    const ushort_t* __restrict__ wE, const float* __restrict__ bE,
    void* __restrict__ out)
{
    __shared__ ushort_t A0[32 * 256];
    __shared__ ushort_t A1[32 * 256];
    const int m0 = blockIdx.x * 32;
    const int t = threadIdx.x;
    const int lane = t & 63, w = t >> 6;
    const int lr = lane & 15, lg = lane >> 4;

#pragma unroll
    for (int i = 0; i < 4; i++) {
        const int r = i * 8 + (t >> 5);
        const int p = t & 31;
        gload16(in + (size_t)(m0 + r) * 256 + ((p ^ (r & 7)) * 8), &A0[i * 2048 + t * 8]);
    }
    __syncthreads();

    layer_to_lds(wA, bA, A0, A1, w, lr, lg);
    __syncthreads();
    if constexpr (THREE) {
        layer_to_lds(wB, bB, A1, A0, w, lr, lg);
        __syncthreads();
        layer_e1(wE, bE, A0, (ushort_t*)out, m0, w, lr, lg);
    } else {
        layer_fin(wB, bB, A1, (float*)out, m0, w, lr, lg);
    }
}

// ---------------------------------------------------------------------------
// Fused edge layer-2 + scatter-mean, v10 + soft barrier (T4-lite).
// Grid 2048 x 256 thr (4 waves). Block = (batch, quad of 4 receivers):
// 128 virtual rows (4 recv x 32 slots, slot31 dummy) x N=256.
// Wave w owns cols [w*64, w*64+64): wave tile 128x64, acc[8][4].
// A tile [128][64] bf16, chunk-swizzled; dbuf 2x16KB. B-frags from the
// L2-resident swizzled image, loaded post-streak, consumed next streak —
// lgkm-only barrier keeps them in flight across the barrier.
__global__ __launch_bounds__(256, 2) void edge_fused(
    const ushort_t* __restrict__ UVb,   // [8192][512] bf16: U'(+b_e1) | V
    const ushort_t* __restrict__ WBsw,  // swizzled w_e2 image
    const float* __restrict__ b2,
    ushort_t* __restrict__ agg)         // [8192][256] bf16
{
    __shared__ ushort_t As[2][128 * 64];   // 16KB each

    const int logical = (blockIdx.x & 7) * 256 + (blockIdx.x >> 3);  // 2048%8==0
    const int bb = logical >> 3;        // batch
    const int g0 = (logical & 7) * 4;   // first receiver of the quad
    const int t = threadIdx.x;
    const int lane = t & 63;
    const int w = t >> 6;
    const int lr = lane & 15, lg = lane >> 4;

    // ---- A-build mapping: thread -> (row, k-half of 32). 2 threads per row.
    const int brow = t >> 1;            // 0..127
    const int kh = t & 1;               // which 32-k half of the 64-k tile
    const int jr = brow >> 5;           // receiver within quad
    const int s = brow & 31;            // slot
    const int j = g0 + jr;
    const int si = (s == 31) ? j : (s + (s >= j ? 1 : 0));
    const ushort_t* up = UVb + (size_t)(bb * 32 + si) * 512 + kh * 32;
    const ushort_t* vp = UVb + (size_t)(bb * 32 + j) * 512 + 256 + kh * 32;
    const int rs7 = brow & 7;
    int aw[4];
#pragma unroll
    for (int i = 0; i < 4; i++)
        aw[i] = brow * 64 + (((kh * 4 + i) ^ rs7) * 8);

    // ---- MFMA-side offsets: af addr = m*1024 + lr*64 + (c^(lr&7))*8, c=ks*4+lg
    const int acof0 = ((lg ^ (lr & 7)) * 8) + lr * 64;   // ks=0 base (+m*1024)
    const int bbase = (w * 64 + lr) * 32 + ((lg ^ ((lr >> 1) & 3)) * 8);  // + fn*512

    auto build = [&](int buf, const uint4* u, const uint4* v) {
#pragma unroll
        for (int i = 0; i < 4; i++) {
            uint4 q;
            q.x = cvt_pk_bf16(fmaxf(lo16f(u[i].x) + lo16f(v[i].x), 0.f),
                              fmaxf(hi16f(u[i].x) + hi16f(v[i].x), 0.f));
            q.y = cvt_pk_bf16(fmaxf(lo16f(u[i].y) + lo16f(v[i].y), 0.f),
                              fmaxf(hi16f(u[i].y) + hi16f(v[i].y), 0.f));
            q.z = cvt_pk_bf16(fmaxf(lo16f(u[i].z) + lo16f(v[i].z), 0.f),
                              fmaxf(hi16f(u[i].z) + hi16f(v[i].z), 0.f));
            q.w = cvt_pk_bf16(fmaxf(lo16f(u[i].w) + lo16f(v[i].w), 0.f),
                              fmaxf(hi16f(u[i].w) + hi16f(v[i].w), 0.f));
            *(uint4*)&As[buf][aw[i]] = q;
        }
    };

    // ---- prologue: build tile 0, load B for step 0
    {
        uint4 u[4], v[4];
#pragma unroll
        for (int i = 0; i < 4; i++) {
            u[i] = *(const uint4*)(up + i * 8);
            v[i] = *(const uint4*)(vp + i * 8);
        }
        build(0, u, v);
    }
    bf16x8 bc[2][4];
#pragma unroll
    for (int ks = 0; ks < 2; ks++)
#pragma unroll
        for (int fn = 0; fn < 4; fn++)
            bc[ks][fn] = *(const bf16x8*)&WBsw[ks * 8192 + bbase + fn * 512];

    f32x4 acc[8][4] = {};

#pragma unroll
    for (int kb = 0; kb < 4; kb++) {
        const int cur = kb & 1;
        soft_barrier();                   // As[cur] built; lgkm drained only
        // issue u/v loads for next build (arrive under the MFMA streak)
        uint4 u[4], v[4];
        if (kb < 3) {
            const ushort_t* upn = up + (kb + 1) * 64;
            const ushort_t* vpn = vp + (kb + 1) * 64;
#pragma unroll
            for (int i = 0; i < 4; i++) {
                u[i] = *(const uint4*)(upn + i * 8);
                v[i] = *(const uint4*)(vpn + i * 8);
            }
        }
        // ---- 64-MFMA streak
        __builtin_amdgcn_s_setprio(1);
#pragma unroll
        for (int ks = 0; ks < 2; ks++) {
            bf16x8 af[8];
#pragma unroll
            for (int m = 0; m < 8; m++)
                af[m] = *(const bf16x8*)&As[cur][m * 1024 + (acof0 ^ (ks * 32))];
#pragma unroll
            for (int fn = 0; fn < 4; fn++)
#pragma unroll
                for (int m = 0; m < 8; m++)
                    acc[m][fn] = __builtin_amdgcn_mfma_f32_16x16x32_bf16(
                        af[m], bc[ks][fn], acc[m][fn], 0, 0, 0);
        }
        __builtin_amdgcn_s_setprio(0);
        if (kb < 3) {
            // next-step B loads: in flight across the next soft barrier
#pragma unroll
            for (int ks = 0; ks < 2; ks++)
#pragma unroll
                for (int fn = 0; fn < 4; fn++)
                    bc[ks][fn] = *(const bf16x8*)&WBsw[((kb + 1) * 2 + ks) * 8192
                                                       + bbase + fn * 512];
            build(cur ^ 1, u, v);         // u/v arrived under the streak
        }
    }

    // ---- Epilogue: bias+relu, sum 31 real slots per receiver, /31, bf16 out.
#pragma unroll
    for (int fn = 0; fn < 4; fn++) {
        const int col = w * 64 + fn * 16 + lr;
        const float bvf = b2[col];
#pragma unroll
        for (int recv = 0; recv < 4; recv++) {
            float sum = 0.f;
#pragma unroll
            for (int q = 0; q < 2; q++) {
                const int fm = recv * 2 + q;
#pragma unroll
                for (int r = 0; r < 4; r++) {
                    float v = fmaxf(acc[fm][fn][r] + bvf, 0.f);
                    if (!(q == 1 && lg == 3 && r == 3)) sum += v;  // skip slot 31
                }
            }
            sum += __shfl_xor(sum, 16);
            sum += __shfl_xor(sum, 32);
            if (lane < 16)
                agg[(size_t)(bb * 32 + g0 + recv) * 256 + col] = f2bf(sum * (1.0f / 31.0f));
        }
    }
}

// ---------------------------------------------------------------------------
extern "C" void kernel_launch(void* const* d_in, const int* in_sizes, int n_in,
                              void* d_out, int out_size, void* d_ws, size_t ws_size,
                              hipStream_t stream)
{
    const float* x     = (const float*)d_in[0];
    const float* w_in1 = (const float*)d_in[3];
    const float* b_in1 = (const float*)d_in[4];
    const float* w_in2 = (const float*)d_in[5];
    const float* b_in2 = (const float*)d_in[6];
    const float* w_e1  = (const float*)d_in[7];
    const float* b_e1  = (const float*)d_in[8];
    const float* w_e2  = (const float*)d_in[9];
    const float* b_e2  = (const float*)d_in[10];
    const float* w_n1  = (const float*)d_in[11];
    const float* b_n1  = (const float*)d_in[12];
    const float* w_n2  = (const float*)d_in[13];
    const float* b_n2  = (const float*)d_in[14];

    char* ws = (char*)d_ws;
    size_t off = 0;
    auto alloc = [&](size_t n) { char* p = ws + off; off += (n + 255) & ~(size_t)255; return p; };

    ushort_t* wt  = (ushort_t*)alloc(7 * 65536 * sizeof(ushort_t));
    ushort_t* xb  = (ushort_t*)alloc(8192 * 256 * 2);
    ushort_t* UVb = (ushort_t*)alloc(8192 * 512 * 2);
    ushort_t* ag  = (ushort_t*)alloc(8192 * 256 * 2);
    (void)ws_size; (void)in_sizes; (void)n_in; (void)out_size;

    prep_all<<<1080, 256, 0, stream>>>(w_in1, w_in2, w_e1, w_e2, w_n1, w_n2, wt, x, xb);

    // pass 0 front: in1 -> in2 -> e1
    mlp_chain<1><<<256, 256, 0, stream>>>(xb,
        wt + 0 * 65536, b_in1, wt + 1 * 65536, b_in2, wt + 2 * 65536, b_e1, UVb);
    edge_fused<<<2048, 256, 0, stream>>>(UVb, wt + 4 * 65536, b_e2, ag);
    // pass 1 front: n1 -> n2 -> e1
    mlp_chain<1><<<256, 256, 0, stream>>>(ag,
        wt + 5 * 65536, b_n1, wt + 6 * 65536, b_n2, wt + 2 * 65536, b_e1, UVb);
    edge_fused<<<2048, 256, 0, stream>>>(UVb, wt + 4 * 65536, b_e2, ag);
    // final: n1 -> n2 (f32 out)
    mlp_chain<0><<<256, 256, 0, stream>>>(ag,
        wt + 5 * 65536, b_n1, wt + 6 * 65536, b_n2, nullptr, nullptr, d_out);
}

// Round 15
// 126.953 us; speedup vs baseline: 1.8806x; 1.0563x over previous
//
#include <hip/hip_runtime.h>

// GNN encoder, B=256, N=32, F=256, fully-connected edges, 2 passes.
// bf16 MFMA 16x16x32, fp32 accum.
// R15 = best-of ledger: edge v10+soft (R14, 46.6us) + 512-thread mlp_chain
// (R11 structure, 2 waves/SIMD) with depth-2 rolling B prefetch (R14).

typedef short bf16x8 __attribute__((ext_vector_type(8)));
typedef float f32x4 __attribute__((ext_vector_type(4)));
typedef unsigned short ushort_t;

__device__ __forceinline__ unsigned short f2bf(float f) {
    unsigned u = __float_as_uint(f);
    u += 0x7fff + ((u >> 16) & 1);   // RNE
    return (unsigned short)(u >> 16);
}
__device__ __forceinline__ float lo16f(unsigned w) { return __uint_as_float(w << 16); }
__device__ __forceinline__ float hi16f(unsigned w) { return __uint_as_float(w & 0xffff0000u); }
__device__ __forceinline__ unsigned cvt_pk_bf16(float lo, float hi) {
    unsigned r;
    asm volatile("v_cvt_pk_bf16_f32 %0, %1, %2" : "=v"(r) : "v"(lo), "v"(hi));
    return r;
}
__device__ __forceinline__ void gload16(const void* g, void* l) {
    __builtin_amdgcn_global_load_lds(
        (const __attribute__((address_space(1))) void*)g,
        (__attribute__((address_space(3))) void*)l, 16, 0, 0);
}
__device__ __forceinline__ void soft_barrier() {
    asm volatile("s_waitcnt lgkmcnt(0)" ::: "memory");
    __builtin_amdgcn_sched_barrier(0);
    __builtin_amdgcn_s_barrier();
}

// ---------------------------------------------------------------------------
// Weight prep (blocks 0..55) + x conversion (blocks 56..1079), merged.
// Weight image: idx = kq*8192 + n*32 + (kc ^ ((n>>1)&3))*8 + (k&7), kq=k>>5.
__global__ __launch_bounds__(256) void prep_all(
    const float* __restrict__ w_in1, const float* __restrict__ w_in2,
    const float* __restrict__ w_e1,  const float* __restrict__ w_e2,
    const float* __restrict__ w_n1,  const float* __restrict__ w_n2,
    ushort_t* __restrict__ dst,
    const float* __restrict__ x, ushort_t* __restrict__ xb)
{
    __shared__ ushort_t tile[32][264];
    const int t = threadIdx.x;
    if (blockIdx.x >= 56) {
        const int i = (blockIdx.x - 56) * 256 + t;
        const float4* p = (const float4*)x + (size_t)i * 2;
        float4 a = p[0], b = p[1];
        ushort4 o0 = make_ushort4(f2bf(a.x), f2bf(a.y), f2bf(a.z), f2bf(a.w));
        ushort4 o1 = make_ushort4(f2bf(b.x), f2bf(b.y), f2bf(b.z), f2bf(b.w));
        ((ushort4*)xb)[(size_t)i * 2]     = o0;
        ((ushort4*)xb)[(size_t)i * 2 + 1] = o1;
        return;
    }
    const int wid = blockIdx.x >> 3;   // 0..6
    const int kb  = blockIdx.x & 7;
    const float* src;
    switch (wid) {
        case 0: src = w_in1; break;
        case 1: src = w_in2; break;
        case 2: src = w_e1; break;              // top half (send side)
        case 3: src = w_e1 + 65536; break;      // bottom half (recv side)
        case 4: src = w_e2; break;
        case 5: src = w_n1; break;
        default: src = w_n2; break;
    }
#pragma unroll
    for (int k0 = 0; k0 < 32; k0++)
        tile[k0][t] = f2bf(src[(size_t)(kb * 32 + k0) * 256 + t]);  // coalesced
    __syncthreads();
    ushort_t* base = dst + wid * 65536 + kb * 8192 + t * 32;
    const int sw = (t >> 1) & 3;
#pragma unroll
    for (int kc = 0; kc < 4; kc++) {
        union { uint4 q; ushort_t u[8]; } w;
#pragma unroll
        for (int ko = 0; ko < 8; ko++) w.u[ko] = tile[kc * 8 + ko][t];
        *(uint4*)&base[(kc ^ sw) * 8] = w.q;
    }
}

// ---------------------------------------------------------------------------
// Fused MLP chain, 512 threads (8 waves, 2 waves/SIMD). Wave w owns a 32-col
// slice (hidden/final layers) or a 64-col slice of 512 (e1 layer).
// A-tiles [32][256] bf16 in LDS, granule swizzle:
//   off = r*256 + ((kc ^ (r&7))*8) + (k&7), kc = k>>3.
// Swapped MFMA: acc = mfma(Wfrag, Xfrag) -> lane holds 4 k-contiguous outputs.
// B prefetch depth 2 (rolling bq[3][..], statically indexed via full unroll).

__device__ __forceinline__ void layer_to_lds(
    const ushort_t* __restrict__ wimg, const float* __restrict__ bias,
    const ushort_t* __restrict__ As, ushort_t* __restrict__ Ad,
    const int w, const int lr, const int lg)
{
    int boffs[2]; float4 b4[2];
#pragma unroll
    for (int fn = 0; fn < 2; fn++) {
        const int n = w * 32 + fn * 16 + lr;
        boffs[fn] = n * 32 + ((lg ^ ((lr >> 1) & 3)) * 8);
        b4[fn] = *(const float4*)&bias[w * 32 + fn * 16 + lg * 4];
    }
    bf16x8 bq[3][2];
#pragma unroll
    for (int fn = 0; fn < 2; fn++) bq[0][fn] = *(const bf16x8*)&wimg[boffs[fn]];
#pragma unroll
    for (int fn = 0; fn < 2; fn++) bq[1][fn] = *(const bf16x8*)&wimg[8192 + boffs[fn]];
    f32x4 acc[2][2] = {};
#pragma unroll
    for (int kb = 0; kb < 8; kb++) {
        if (kb < 6)
#pragma unroll
            for (int fn = 0; fn < 2; fn++)
                bq[(kb + 2) % 3][fn] = *(const bf16x8*)&wimg[(kb + 2) * 8192 + boffs[fn]];
        bf16x8 af[2];
#pragma unroll
        for (int fm = 0; fm < 2; fm++) {
            const int r = fm * 16 + lr;
            af[fm] = *(const bf16x8*)&As[r * 256 + (((kb * 4 + lg) ^ (r & 7)) * 8)];
        }
#pragma unroll
        for (int fn = 0; fn < 2; fn++)
#pragma unroll
            for (int fm = 0; fm < 2; fm++)
                acc[fn][fm] = __builtin_amdgcn_mfma_f32_16x16x32_bf16(
                    bq[kb % 3][fn], af[fm], acc[fn][fm], 0, 0, 0);
    }
#pragma unroll
    for (int fn = 0; fn < 2; fn++) {
        const int k0 = w * 32 + fn * 16 + lg * 4;     // output col = next-layer k
        const int kc = k0 >> 3, kj = k0 & 7;
#pragma unroll
        for (int fm = 0; fm < 2; fm++) {
            const int m = fm * 16 + lr;
            float v0 = fmaxf(acc[fn][fm][0] + b4[fn].x, 0.f);
            float v1 = fmaxf(acc[fn][fm][1] + b4[fn].y, 0.f);
            float v2 = fmaxf(acc[fn][fm][2] + b4[fn].z, 0.f);
            float v3 = fmaxf(acc[fn][fm][3] + b4[fn].w, 0.f);
            uint2 q = { cvt_pk_bf16(v0, v1), cvt_pk_bf16(v2, v3) };
            *(uint2*)&Ad[m * 256 + ((kc ^ (m & 7)) * 8) + kj] = q;
        }
    }
}

__device__ __forceinline__ void layer_e1(
    const ushort_t* __restrict__ wE, const float* __restrict__ bE,
    const ushort_t* __restrict__ As, ushort_t* __restrict__ UVb,
    const int m0, const int w, const int lr, const int lg)
{
    const ushort_t* wimg = (w < 4) ? wE : (wE + 65536);
    const int nb = (w & 3) * 64;
    int boffs[4]; float4 b4[4];
#pragma unroll
    for (int fn = 0; fn < 4; fn++) {
        const int n = nb + fn * 16 + lr;
        boffs[fn] = n * 32 + ((lg ^ ((lr >> 1) & 3)) * 8);
        if (w < 4) b4[fn] = *(const float4*)&bE[nb + fn * 16 + lg * 4];
        else       b4[fn] = make_float4(0.f, 0.f, 0.f, 0.f);
    }
    bf16x8 bq[3][4];
#pragma unroll
    for (int fn = 0; fn < 4; fn++) bq[0][fn] = *(const bf16x8*)&wimg[boffs[fn]];
#pragma unroll
    for (int fn = 0; fn < 4; fn++) bq[1][fn] = *(const bf16x8*)&wimg[8192 + boffs[fn]];
    f32x4 acc[4][2] = {};
#pragma unroll
    for (int kb = 0; kb < 8; kb++) {
        if (kb < 6)
#pragma unroll
            for (int fn = 0; fn < 4; fn++)
                bq[(kb + 2) % 3][fn] = *(const bf16x8*)&wimg[(kb + 2) * 8192 + boffs[fn]];
        bf16x8 af[2];
#pragma unroll
        for (int fm = 0; fm < 2; fm++) {
            const int r = fm * 16 + lr;
            af[fm] = *(const bf16x8*)&As[r * 256 + (((kb * 4 + lg) ^ (r & 7)) * 8)];
        }
#pragma unroll
        for (int fn = 0; fn < 4; fn++)
#pragma unroll
            for (int fm = 0; fm < 2; fm++)
                acc[fn][fm] = __builtin_amdgcn_mfma_f32_16x16x32_bf16(
                    bq[kb % 3][fn], af[fm], acc[fn][fm], 0, 0, 0);
    }
#pragma unroll
    for (int fn = 0; fn < 4; fn++) {
        const int nglob = w * 64 + fn * 16 + lg * 4;
#pragma unroll
        for (int fm = 0; fm < 2; fm++) {
            const int node = m0 + fm * 16 + lr;
            float v0 = acc[fn][fm][0] + b4[fn].x;
            float v1 = acc[fn][fm][1] + b4[fn].y;
            float v2 = acc[fn][fm][2] + b4[fn].z;
            float v3 = acc[fn][fm][3] + b4[fn].w;
            uint2 q = { cvt_pk_bf16(v0, v1), cvt_pk_bf16(v2, v3) };
            *(uint2*)&UVb[(size_t)node * 512 + nglob] = q;
        }
    }
}

__device__ __forceinline__ void layer_fin(
    const ushort_t* __restrict__ wimg, const float* __restrict__ bias,
    const ushort_t* __restrict__ As, float* __restrict__ out,
    const int m0, const int w, const int lr, const int lg)
{
    int boffs[2]; float4 b4[2];
#pragma unroll
    for (int fn = 0; fn < 2; fn++) {
        const int n = w * 32 + fn * 16 + lr;
        boffs[fn] = n * 32 + ((lg ^ ((lr >> 1) & 3)) * 8);
        b4[fn] = *(const float4*)&bias[w * 32 + fn * 16 + lg * 4];
    }
    bf16x8 bq[3][2];
#pragma unroll
    for (int fn = 0; fn < 2; fn++) bq[0][fn] = *(const bf16x8*)&wimg[boffs[fn]];
#pragma unroll
    for (int fn = 0; fn < 2; fn++) bq[1][fn] = *(const bf16x8*)&wimg[8192 + boffs[fn]];
    f32x4 acc[2][2] = {};
#pragma unroll
    for (int kb = 0; kb < 8; kb++) {
        if (kb < 6)
#pragma unroll
            for (int fn = 0; fn < 2; fn++)
                bq[(kb + 2) % 3][fn] = *(const bf16x8*)&wimg[(kb + 2) * 8192 + boffs[fn]];
        bf16x8 af[2];
#pragma unroll
        for (int fm = 0; fm < 2; fm++) {
            const int r = fm * 16 + lr;
            af[fm] = *(const bf16x8*)&As[r * 256 + (((kb * 4 + lg) ^ (r & 7)) * 8)];
        }
#pragma unroll
        for (int fn = 0; fn < 2; fn++)
#pragma unroll
            for (int fm = 0; fm < 2; fm++)
                acc[fn][fm] = __builtin_amdgcn_mfma_f32_16x16x32_bf16(
                    bq[kb % 3][fn], af[fm], acc[fn][fm], 0, 0, 0);
    }
#pragma unroll
    for (int fn = 0; fn < 2; fn++) {
        const int col = w * 32 + fn * 16 + lg * 4;
#pragma unroll
        for (int fm = 0; fm < 2; fm++) {
            const int row = m0 + fm * 16 + lr;
            float4 o;
            o.x = fmaxf(acc[fn][fm][0] + b4[fn].x, 0.f);
            o.y = fmaxf(acc[fn][fm][1] + b4[fn].y, 0.f);
            o.z = fmaxf(acc[fn][fm][2] + b4[fn].z, 0.f);
            o.w = fmaxf(acc[fn][fm][3] + b4[fn].w, 0.f);
            *(float4*)&out[(size_t)row * 256 + col] = o;
        }
    }
}

template <int THREE>
__global__ __launch_bounds__(512, 2) void mlp_chain(
    const ushort_t* __restrict__ in,
    const ushort_t* __restrict__ wA, const float* __restrict__ bA,
    const ushort_t* __restrict__ wB, const float* __restrict__ bB,
    const ushort_t* __restrict__ wE, const float* __restrict__ bE,
    void* __restrict__ out)
{
    __shared__ ushort_t A0[32 * 256];
    __shared__ ushort_t A1[32 * 256];
    const int m0 = blockIdx.x * 32;
    const int t = threadIdx.x;
    const int lane = t & 63, w = t >> 6;
    const int lr = lane & 15, lg = lane >> 4;

    // stage input tile: thread covers elems [t*8, +8) and [(t+512)*8, +8)
    {
        const int r0 = t >> 5, p0 = t & 31;
        gload16(in + (size_t)(m0 + r0) * 256 + ((p0 ^ (r0 & 7)) * 8), &A0[t * 8]);
        const int r1 = r0 + 16;
        gload16(in + (size_t)(m0 + r1) * 256 + ((p0 ^ (r1 & 7)) * 8), &A0[(t + 512) * 8]);
    }
    __syncthreads();

    layer_to_lds(wA, bA, A0, A1, w, lr, lg);
    __syncthreads();
    if constexpr (THREE) {
        layer_to_lds(wB, bB, A1, A0, w, lr, lg);
        __syncthreads();
        layer_e1(wE, bE, A0, (ushort_t*)out, m0, w, lr, lg);
    } else {
        layer_fin(wB, bB, A1, (float*)out, m0, w, lr, lg);
    }
}

// ---------------------------------------------------------------------------
// Fused edge layer-2 + scatter-mean (R14 = v10 + soft barrier, best measured).
// Grid 2048 x 256 thr (4 waves). Block = (batch, quad of 4 receivers):
// 128 virtual rows (4 recv x 32 slots, slot31 dummy) x N=256.
// Wave w owns cols [w*64, w*64+64): wave tile 128x64, acc[8][4].
__global__ __launch_bounds__(256, 2) void edge_fused(
    const ushort_t* __restrict__ UVb,   // [8192][512] bf16: U'(+b_e1) | V
    const ushort_t* __restrict__ WBsw,  // swizzled w_e2 image
    const float* __restrict__ b2,
    ushort_t* __restrict__ agg)         // [8192][256] bf16
{
    __shared__ ushort_t As[2][128 * 64];   // 16KB each

    const int logical = (blockIdx.x & 7) * 256 + (blockIdx.x >> 3);  // 2048%8==0
    const int bb = logical >> 3;        // batch
    const int g0 = (logical & 7) * 4;   // first receiver of the quad
    const int t = threadIdx.x;
    const int lane = t & 63;
    const int w = t >> 6;
    const int lr = lane & 15, lg = lane >> 4;

    const int brow = t >> 1;            // 0..127
    const int kh = t & 1;
    const int jr = brow >> 5;
    const int s = brow & 31;
    const int j = g0 + jr;
    const int si = (s == 31) ? j : (s + (s >= j ? 1 : 0));
    const ushort_t* up = UVb + (size_t)(bb * 32 + si) * 512 + kh * 32;
    const ushort_t* vp = UVb + (size_t)(bb * 32 + j) * 512 + 256 + kh * 32;
    const int rs7 = brow & 7;
    int aw[4];
#pragma unroll
    for (int i = 0; i < 4; i++)
        aw[i] = brow * 64 + (((kh * 4 + i) ^ rs7) * 8);

    const int acof0 = ((lg ^ (lr & 7)) * 8) + lr * 64;   // ks=0 base (+m*1024)
    const int bbase = (w * 64 + lr) * 32 + ((lg ^ ((lr >> 1) & 3)) * 8);  // + fn*512

    auto build = [&](int buf, const uint4* u, const uint4* v) {
#pragma unroll
        for (int i = 0; i < 4; i++) {
            uint4 q;
            q.x = cvt_pk_bf16(fmaxf(lo16f(u[i].x) + lo16f(v[i].x), 0.f),
                              fmaxf(hi16f(u[i].x) + hi16f(v[i].x), 0.f));
            q.y = cvt_pk_bf16(fmaxf(lo16f(u[i].y) + lo16f(v[i].y), 0.f),
                              fmaxf(hi16f(u[i].y) + hi16f(v[i].y), 0.f));
            q.z = cvt_pk_bf16(fmaxf(lo16f(u[i].z) + lo16f(v[i].z), 0.f),
                              fmaxf(hi16f(u[i].z) + hi16f(v[i].z), 0.f));
            q.w = cvt_pk_bf16(fmaxf(lo16f(u[i].w) + lo16f(v[i].w), 0.f),
                              fmaxf(hi16f(u[i].w) + hi16f(v[i].w), 0.f));
            *(uint4*)&As[buf][aw[i]] = q;
        }
    };

    // prologue: build tile 0, load B for step 0
    {
        uint4 u[4], v[4];
#pragma unroll
        for (int i = 0; i < 4; i++) {
            u[i] = *(const uint4*)(up + i * 8);
            v[i] = *(const uint4*)(vp + i * 8);
        }
        build(0, u, v);
    }
    bf16x8 bc[2][4];
#pragma unroll
    for (int ks = 0; ks < 2; ks++)
#pragma unroll
        for (int fn = 0; fn < 4; fn++)
            bc[ks][fn] = *(const bf16x8*)&WBsw[ks * 8192 + bbase + fn * 512];

    f32x4 acc[8][4] = {};

#pragma unroll
    for (int kb = 0; kb < 4; kb++) {
        const int cur = kb & 1;
        soft_barrier();                   // As[cur] built; lgkm drained only
        uint4 u[4], v[4];
        if (kb < 3) {
            const ushort_t* upn = up + (kb + 1) * 64;
            const ushort_t* vpn = vp + (kb + 1) * 64;
#pragma unroll
            for (int i = 0; i < 4; i++) {
                u[i] = *(const uint4*)(upn + i * 8);
                v[i] = *(const uint4*)(vpn + i * 8);
            }
        }
        // ---- 64-MFMA streak
        __builtin_amdgcn_s_setprio(1);
#pragma unroll
        for (int ks = 0; ks < 2; ks++) {
            bf16x8 af[8];
#pragma unroll
            for (int m = 0; m < 8; m++)
                af[m] = *(const bf16x8*)&As[cur][m * 1024 + (acof0 ^ (ks * 32))];
#pragma unroll
            for (int fn = 0; fn < 4; fn++)
#pragma unroll
                for (int m = 0; m < 8; m++)
                    acc[m][fn] = __builtin_amdgcn_mfma_f32_16x16x32_bf16(
                        af[m], bc[ks][fn], acc[m][fn], 0, 0, 0);
        }
        __builtin_amdgcn_s_setprio(0);
        if (kb < 3) {
#pragma unroll
            for (int ks = 0; ks < 2; ks++)
#pragma unroll
                for (int fn = 0; fn < 4; fn++)
                    bc[ks][fn] = *(const bf16x8*)&WBsw[((kb + 1) * 2 + ks) * 8192
                                                       + bbase + fn * 512];
            build(cur ^ 1, u, v);
        }
    }

    // ---- Epilogue: bias+relu, sum 31 real slots per receiver, /31, bf16 out.
#pragma unroll
    for (int fn = 0; fn < 4; fn++) {
        const int col = w * 64 + fn * 16 + lr;
        const float bvf = b2[col];
#pragma unroll
        for (int recv = 0; recv < 4; recv++) {
            float sum = 0.f;
#pragma unroll
            for (int q = 0; q < 2; q++) {
                const int fm = recv * 2 + q;
#pragma unroll
                for (int r = 0; r < 4; r++) {
                    float v = fmaxf(acc[fm][fn][r] + bvf, 0.f);
                    if (!(q == 1 && lg == 3 && r == 3)) sum += v;  // skip slot 31
                }
            }
            sum += __shfl_xor(sum, 16);
            sum += __shfl_xor(sum, 32);
            if (lane < 16)
                agg[(size_t)(bb * 32 + g0 + recv) * 256 + col] = f2bf(sum * (1.0f / 31.0f));
        }
    }
}

// ---------------------------------------------------------------------------
extern "C" void kernel_launch(void* const* d_in, const int* in_sizes, int n_in,
                              void* d_out, int out_size, void* d_ws, size_t ws_size,
                              hipStream_t stream)
{
    const float* x     = (const float*)d_in[0];
    const float* w_in1 = (const float*)d_in[3];
    const float* b_in1 = (const float*)d_in[4];
    const float* w_in2 = (const float*)d_in[5];
    const float* b_in2 = (const float*)d_in[6];
    const float* w_e1  = (const float*)d_in[7];
    const float* b_e1  = (const float*)d_in[8];
    const float* w_e2  = (const float*)d_in[9];
    const float* b_e2  = (const float*)d_in[10];
    const float* w_n1  = (const float*)d_in[11];
    const float* b_n1  = (const float*)d_in[12];
    const float* w_n2  = (const float*)d_in[13];
    const float* b_n2  = (const float*)d_in[14];

    char* ws = (char*)d_ws;
    size_t off = 0;
    auto alloc = [&](size_t n) { char* p = ws + off; off += (n + 255) & ~(size_t)255; return p; };

    ushort_t* wt  = (ushort_t*)alloc(7 * 65536 * sizeof(ushort_t));
    ushort_t* xb  = (ushort_t*)alloc(8192 * 256 * 2);
    ushort_t* UVb = (ushort_t*)alloc(8192 * 512 * 2);
    ushort_t* ag  = (ushort_t*)alloc(8192 * 256 * 2);
    (void)ws_size; (void)in_sizes; (void)n_in; (void)out_size;

    prep_all<<<1080, 256, 0, stream>>>(w_in1, w_in2, w_e1, w_e2, w_n1, w_n2, wt, x, xb);

    // pass 0 front: in1 -> in2 -> e1
    mlp_chain<1><<<256, 512, 0, stream>>>(xb,
        wt + 0 * 65536, b_in1, wt + 1 * 65536, b_in2, wt + 2 * 65536, b_e1, UVb);
    edge_fused<<<2048, 256, 0, stream>>>(UVb, wt + 4 * 65536, b_e2, ag);
    // pass 1 front: n1 -> n2 -> e1
    mlp_chain<1><<<256, 512, 0, stream>>>(ag,
        wt + 5 * 65536, b_n1, wt + 6 * 65536, b_n2, wt + 2 * 65536, b_e1, UVb);
    edge_fused<<<2048, 256, 0, stream>>>(UVb, wt + 4 * 65536, b_e2, ag);
    // final: n1 -> n2 (f32 out)
    mlp_chain<0><<<256, 512, 0, stream>>>(ag,
        wt + 5 * 65536, b_n1, wt + 6 * 65536, b_n2, nullptr, nullptr, d_out);
}

// Round 16
// 124.050 us; speedup vs baseline: 1.9246x; 1.0234x over previous
//
#include <hip/hip_runtime.h>

// GNN encoder, B=256, N=32, F=256, fully-connected edges, 2 passes.
// R16 = R15 (126.95us) with edge v16: 32x32x16 MFMA (same geometry,
// +15% matrix rate, half the MFMA instructions, 1-shuffle epilogue).

typedef short bf16x8 __attribute__((ext_vector_type(8)));
typedef float f32x4 __attribute__((ext_vector_type(4)));
typedef float f32x16 __attribute__((ext_vector_type(16)));
typedef unsigned short ushort_t;

__device__ __forceinline__ unsigned short f2bf(float f) {
    unsigned u = __float_as_uint(f);
    u += 0x7fff + ((u >> 16) & 1);   // RNE
    return (unsigned short)(u >> 16);
}
__device__ __forceinline__ float lo16f(unsigned w) { return __uint_as_float(w << 16); }
__device__ __forceinline__ float hi16f(unsigned w) { return __uint_as_float(w & 0xffff0000u); }
__device__ __forceinline__ unsigned cvt_pk_bf16(float lo, float hi) {
    unsigned r;
    asm volatile("v_cvt_pk_bf16_f32 %0, %1, %2" : "=v"(r) : "v"(lo), "v"(hi));
    return r;
}
__device__ __forceinline__ void gload16(const void* g, void* l) {
    __builtin_amdgcn_global_load_lds(
        (const __attribute__((address_space(1))) void*)g,
        (__attribute__((address_space(3))) void*)l, 16, 0, 0);
}
__device__ __forceinline__ void soft_barrier() {
    asm volatile("s_waitcnt lgkmcnt(0)" ::: "memory");
    __builtin_amdgcn_sched_barrier(0);
    __builtin_amdgcn_s_barrier();
}

// ---------------------------------------------------------------------------
// Weight prep (blocks 0..55) + x conversion (blocks 56..1079), merged.
// Weight image: idx = kq*8192 + n*32 + (kc ^ ((n>>1)&3))*8 + (k&7), kq=k>>5.
__global__ __launch_bounds__(256) void prep_all(
    const float* __restrict__ w_in1, const float* __restrict__ w_in2,
    const float* __restrict__ w_e1,  const float* __restrict__ w_e2,
    const float* __restrict__ w_n1,  const float* __restrict__ w_n2,
    ushort_t* __restrict__ dst,
    const float* __restrict__ x, ushort_t* __restrict__ xb)
{
    __shared__ ushort_t tile[32][264];
    const int t = threadIdx.x;
    if (blockIdx.x >= 56) {
        const int i = (blockIdx.x - 56) * 256 + t;
        const float4* p = (const float4*)x + (size_t)i * 2;
        float4 a = p[0], b = p[1];
        ushort4 o0 = make_ushort4(f2bf(a.x), f2bf(a.y), f2bf(a.z), f2bf(a.w));
        ushort4 o1 = make_ushort4(f2bf(b.x), f2bf(b.y), f2bf(b.z), f2bf(b.w));
        ((ushort4*)xb)[(size_t)i * 2]     = o0;
        ((ushort4*)xb)[(size_t)i * 2 + 1] = o1;
        return;
    }
    const int wid = blockIdx.x >> 3;   // 0..6
    const int kb  = blockIdx.x & 7;
    const float* src;
    switch (wid) {
        case 0: src = w_in1; break;
        case 1: src = w_in2; break;
        case 2: src = w_e1; break;              // top half (send side)
        case 3: src = w_e1 + 65536; break;      // bottom half (recv side)
        case 4: src = w_e2; break;
        case 5: src = w_n1; break;
        default: src = w_n2; break;
    }
#pragma unroll
    for (int k0 = 0; k0 < 32; k0++)
        tile[k0][t] = f2bf(src[(size_t)(kb * 32 + k0) * 256 + t]);  // coalesced
    __syncthreads();
    ushort_t* base = dst + wid * 65536 + kb * 8192 + t * 32;
    const int sw = (t >> 1) & 3;
#pragma unroll
    for (int kc = 0; kc < 4; kc++) {
        union { uint4 q; ushort_t u[8]; } w;
#pragma unroll
        for (int ko = 0; ko < 8; ko++) w.u[ko] = tile[kc * 8 + ko][t];
        *(uint4*)&base[(kc ^ sw) * 8] = w.q;
    }
}

// ---------------------------------------------------------------------------
// Fused MLP chain, 512 threads (8 waves, 2 waves/SIMD). Wave w owns a 32-col
// slice (hidden/final layers) or a 64-col slice of 512 (e1 layer).
// A-tiles [32][256] bf16 in LDS, granule swizzle:
//   off = r*256 + ((kc ^ (r&7))*8) + (k&7), kc = k>>3.
// Swapped MFMA: acc = mfma(Wfrag, Xfrag) -> lane holds 4 k-contiguous outputs.
// B prefetch depth 2 (rolling bq[3][..], statically indexed via full unroll).

__device__ __forceinline__ void layer_to_lds(
    const ushort_t* __restrict__ wimg, const float* __restrict__ bias,
    const ushort_t* __restrict__ As, ushort_t* __restrict__ Ad,
    const int w, const int lr, const int lg)
{
    int boffs[2]; float4 b4[2];
#pragma unroll
    for (int fn = 0; fn < 2; fn++) {
        const int n = w * 32 + fn * 16 + lr;
        boffs[fn] = n * 32 + ((lg ^ ((lr >> 1) & 3)) * 8);
        b4[fn] = *(const float4*)&bias[w * 32 + fn * 16 + lg * 4];
    }
    bf16x8 bq[3][2];
#pragma unroll
    for (int fn = 0; fn < 2; fn++) bq[0][fn] = *(const bf16x8*)&wimg[boffs[fn]];
#pragma unroll
    for (int fn = 0; fn < 2; fn++) bq[1][fn] = *(const bf16x8*)&wimg[8192 + boffs[fn]];
    f32x4 acc[2][2] = {};
#pragma unroll
    for (int kb = 0; kb < 8; kb++) {
        if (kb < 6)
#pragma unroll
            for (int fn = 0; fn < 2; fn++)
                bq[(kb + 2) % 3][fn] = *(const bf16x8*)&wimg[(kb + 2) * 8192 + boffs[fn]];
        bf16x8 af[2];
#pragma unroll
        for (int fm = 0; fm < 2; fm++) {
            const int r = fm * 16 + lr;
            af[fm] = *(const bf16x8*)&As[r * 256 + (((kb * 4 + lg) ^ (r & 7)) * 8)];
        }
#pragma unroll
        for (int fn = 0; fn < 2; fn++)
#pragma unroll
            for (int fm = 0; fm < 2; fm++)
                acc[fn][fm] = __builtin_amdgcn_mfma_f32_16x16x32_bf16(
                    bq[kb % 3][fn], af[fm], acc[fn][fm], 0, 0, 0);
    }
#pragma unroll
    for (int fn = 0; fn < 2; fn++) {
        const int k0 = w * 32 + fn * 16 + lg * 4;     // output col = next-layer k
        const int kc = k0 >> 3, kj = k0 & 7;
#pragma unroll
        for (int fm = 0; fm < 2; fm++) {
            const int m = fm * 16 + lr;
            float v0 = fmaxf(acc[fn][fm][0] + b4[fn].x, 0.f);
            float v1 = fmaxf(acc[fn][fm][1] + b4[fn].y, 0.f);
            float v2 = fmaxf(acc[fn][fm][2] + b4[fn].z, 0.f);
            float v3 = fmaxf(acc[fn][fm][3] + b4[fn].w, 0.f);
            uint2 q = { cvt_pk_bf16(v0, v1), cvt_pk_bf16(v2, v3) };
            *(uint2*)&Ad[m * 256 + ((kc ^ (m & 7)) * 8) + kj] = q;
        }
    }
}

__device__ __forceinline__ void layer_e1(
    const ushort_t* __restrict__ wE, const float* __restrict__ bE,
    const ushort_t* __restrict__ As, ushort_t* __restrict__ UVb,
    const int m0, const int w, const int lr, const int lg)
{
    const ushort_t* wimg = (w < 4) ? wE : (wE + 65536);
    const int nb = (w & 3) * 64;
    int boffs[4]; float4 b4[4];
#pragma unroll
    for (int fn = 0; fn < 4; fn++) {
        const int n = nb + fn * 16 + lr;
        boffs[fn] = n * 32 + ((lg ^ ((lr >> 1) & 3)) * 8);
        if (w < 4) b4[fn] = *(const float4*)&bE[nb + fn * 16 + lg * 4];
        else       b4[fn] = make_float4(0.f, 0.f, 0.f, 0.f);
    }
    bf16x8 bq[3][4];
#pragma unroll
    for (int fn = 0; fn < 4; fn++) bq[0][fn] = *(const bf16x8*)&wimg[boffs[fn]];
#pragma unroll
    for (int fn = 0; fn < 4; fn++) bq[1][fn] = *(const bf16x8*)&wimg[8192 + boffs[fn]];
    f32x4 acc[4][2] = {};
#pragma unroll
    for (int kb = 0; kb < 8; kb++) {
        if (kb < 6)
#pragma unroll
            for (int fn = 0; fn < 4; fn++)
                bq[(kb + 2) % 3][fn] = *(const bf16x8*)&wimg[(kb + 2) * 8192 + boffs[fn]];
        bf16x8 af[2];
#pragma unroll
        for (int fm = 0; fm < 2; fm++) {
            const int r = fm * 16 + lr;
            af[fm] = *(const bf16x8*)&As[r * 256 + (((kb * 4 + lg) ^ (r & 7)) * 8)];
        }
#pragma unroll
        for (int fn = 0; fn < 4; fn++)
#pragma unroll
            for (int fm = 0; fm < 2; fm++)
                acc[fn][fm] = __builtin_amdgcn_mfma_f32_16x16x32_bf16(
                    bq[kb % 3][fn], af[fm], acc[fn][fm], 0, 0, 0);
    }
#pragma unroll
    for (int fn = 0; fn < 4; fn++) {
        const int nglob = w * 64 + fn * 16 + lg * 4;
#pragma unroll
        for (int fm = 0; fm < 2; fm++) {
            const int node = m0 + fm * 16 + lr;
            float v0 = acc[fn][fm][0] + b4[fn].x;
            float v1 = acc[fn][fm][1] + b4[fn].y;
            float v2 = acc[fn][fm][2] + b4[fn].z;
            float v3 = acc[fn][fm][3] + b4[fn].w;
            uint2 q = { cvt_pk_bf16(v0, v1), cvt_pk_bf16(v2, v3) };
            *(uint2*)&UVb[(size_t)node * 512 + nglob] = q;
        }
    }
}

__device__ __forceinline__ void layer_fin(
    const ushort_t* __restrict__ wimg, const float* __restrict__ bias,
    const ushort_t* __restrict__ As, float* __restrict__ out,
    const int m0, const int w, const int lr, const int lg)
{
    int boffs[2]; float4 b4[2];
#pragma unroll
    for (int fn = 0; fn < 2; fn++) {
        const int n = w * 32 + fn * 16 + lr;
        boffs[fn] = n * 32 + ((lg ^ ((lr >> 1) & 3)) * 8);
        b4[fn] = *(const float4*)&bias[w * 32 + fn * 16 + lg * 4];
    }
    bf16x8 bq[3][2];
#pragma unroll
    for (int fn = 0; fn < 2; fn++) bq[0][fn] = *(const bf16x8*)&wimg[boffs[fn]];
#pragma unroll
    for (int fn = 0; fn < 2; fn++) bq[1][fn] = *(const bf16x8*)&wimg[8192 + boffs[fn]];
    f32x4 acc[2][2] = {};
#pragma unroll
    for (int kb = 0; kb < 8; kb++) {
        if (kb < 6)
#pragma unroll
            for (int fn = 0; fn < 2; fn++)
                bq[(kb + 2) % 3][fn] = *(const bf16x8*)&wimg[(kb + 2) * 8192 + boffs[fn]];
        bf16x8 af[2];
#pragma unroll
        for (int fm = 0; fm < 2; fm++) {
            const int r = fm * 16 + lr;
            af[fm] = *(const bf16x8*)&As[r * 256 + (((kb * 4 + lg) ^ (r & 7)) * 8)];
        }
#pragma unroll
        for (int fn = 0; fn < 2; fn++)
#pragma unroll
            for (int fm = 0; fm < 2; fm++)
                acc[fn][fm] = __builtin_amdgcn_mfma_f32_16x16x32_bf16(
                    bq[kb % 3][fn], af[fm], acc[fn][fm], 0, 0, 0);
    }
#pragma unroll
    for (int fn = 0; fn < 2; fn++) {
        const int col = w * 32 + fn * 16 + lg * 4;
#pragma unroll
        for (int fm = 0; fm < 2; fm++) {
            const int row = m0 + fm * 16 + lr;
            float4 o;
            o.x = fmaxf(acc[fn][fm][0] + b4[fn].x, 0.f);
            o.y = fmaxf(acc[fn][fm][1] + b4[fn].y, 0.f);
            o.z = fmaxf(acc[fn][fm][2] + b4[fn].z, 0.f);
            o.w = fmaxf(acc[fn][fm][3] + b4[fn].w, 0.f);
            *(float4*)&out[(size_t)row * 256 + col] = o;
        }
    }
}

template <int THREE>
__global__ __launch_bounds__(512, 2) void mlp_chain(
    const ushort_t* __restrict__ in,
    const ushort_t* __restrict__ wA, const float* __restrict__ bA,
    const ushort_t* __restrict__ wB, const float* __restrict__ bB,
    const ushort_t* __restrict__ wE, const float* __restrict__ bE,
    void* __restrict__ out)
{
    __shared__ ushort_t A0[32 * 256];
    __shared__ ushort_t A1[32 * 256];
    const int m0 = blockIdx.x * 32;
    const int t = threadIdx.x;
    const int lane = t & 63, w = t >> 6;
    const int lr = lane & 15, lg = lane >> 4;

    {
        const int r0 = t >> 5, p0 = t & 31;
        gload16(in + (size_t)(m0 + r0) * 256 + ((p0 ^ (r0 & 7)) * 8), &A0[t * 8]);
        const int r1 = r0 + 16;
        gload16(in + (size_t)(m0 + r1) * 256 + ((p0 ^ (r1 & 7)) * 8), &A0[(t + 512) * 8]);
    }
    __syncthreads();

    layer_to_lds(wA, bA, A0, A1, w, lr, lg);
    __syncthreads();
    if constexpr (THREE) {
        layer_to_lds(wB, bB, A1, A0, w, lr, lg);
        __syncthreads();
        layer_e1(wE, bE, A0, (ushort_t*)out, m0, w, lr, lg);
    } else {
        layer_fin(wB, bB, A1, (float*)out, m0, w, lr, lg);
    }
}

// ---------------------------------------------------------------------------
// Fused edge layer-2 + scatter-mean, v16: 32x32x16 MFMA.
// Grid 2048 x 256 thr (4 waves). Block = (batch, quad of 4 receivers):
// 128 virtual rows (4 recv x 32 slots, slot31 dummy) x N=256.
// Wave w owns cols [w*64, w*64+64): 4 m-tiles x 2 n-tiles of 32x32,
// acc = f32x16[4][2] (128 AGPRs). A tile [128][64] bf16 chunk-swizzled,
// dbuf 2x16KB; B-frags from L2-resident swizzled image, post-streak prefetch;
// soft (lgkm-only) barrier.
__global__ __launch_bounds__(256, 2) void edge_fused(
    const ushort_t* __restrict__ UVb,   // [8192][512] bf16: U'(+b_e1) | V
    const ushort_t* __restrict__ WBsw,  // swizzled w_e2 image
    const float* __restrict__ b2,
    ushort_t* __restrict__ agg)         // [8192][256] bf16
{
    __shared__ ushort_t As[2][128 * 64];   // 16KB each

    const int logical = (blockIdx.x & 7) * 256 + (blockIdx.x >> 3);  // 2048%8==0
    const int bb = logical >> 3;        // batch
    const int g0 = (logical & 7) * 4;   // first receiver of the quad
    const int t = threadIdx.x;
    const int lane = t & 63;
    const int w = t >> 6;
    const int l31 = lane & 31;
    const int hg = lane >> 5;           // k half-granule select

    // ---- A-build mapping (v10): 2 threads/row, 4 chunks (32 elems) each
    const int brow = t >> 1;            // 0..127
    const int kh = t & 1;               // which 32-k half of the 64-k tile
    const int jr = brow >> 5;           // receiver within quad
    const int s = brow & 31;            // slot
    const int j = g0 + jr;
    const int si = (s == 31) ? j : (s + (s >= j ? 1 : 0));
    const ushort_t* up = UVb + (size_t)(bb * 32 + si) * 512 + kh * 32;
    const ushort_t* vp = UVb + (size_t)(bb * 32 + j) * 512 + 256 + kh * 32;
    const int rs7 = brow & 7;
    int aw[4];
#pragma unroll
    for (int i = 0; i < 4; i++)
        aw[i] = brow * 64 + (((kh * 4 + i) ^ rs7) * 8);

    // ---- MFMA-side offsets
    // A frag (mt, k16): row r = mt*32 + l31, granule c = k16*2 + hg:
    //   addr = r*64 + ((c ^ (r&7))*8)
    int abase[4];
#pragma unroll
    for (int mt = 0; mt < 4; mt++) abase[mt] = (mt * 32 + l31) * 64;
    const int r7 = l31 & 7;
    // B frag (nt, k16): n = w*64 + nt*32 + l31, k = kb*64 + k16*16 + hg*8:
    //   img = (kb*2 + (k16>>1))*8192 + n*32 + (((k16&1)*2 + hg) ^ ((n>>1)&3))*8
    int nb32[2], nsw[2];
#pragma unroll
    for (int nt = 0; nt < 2; nt++) {
        const int n = w * 64 + nt * 32 + l31;
        nb32[nt] = n * 32;
        nsw[nt] = (n >> 1) & 3;
    }

    auto build = [&](int buf, const uint4* u, const uint4* v) {
#pragma unroll
        for (int i = 0; i < 4; i++) {
            uint4 q;
            q.x = cvt_pk_bf16(fmaxf(lo16f(u[i].x) + lo16f(v[i].x), 0.f),
                              fmaxf(hi16f(u[i].x) + hi16f(v[i].x), 0.f));
            q.y = cvt_pk_bf16(fmaxf(lo16f(u[i].y) + lo16f(v[i].y), 0.f),
                              fmaxf(hi16f(u[i].y) + hi16f(v[i].y), 0.f));
            q.z = cvt_pk_bf16(fmaxf(lo16f(u[i].z) + lo16f(v[i].z), 0.f),
                              fmaxf(hi16f(u[i].z) + hi16f(v[i].z), 0.f));
            q.w = cvt_pk_bf16(fmaxf(lo16f(u[i].w) + lo16f(v[i].w), 0.f),
                              fmaxf(hi16f(u[i].w) + hi16f(v[i].w), 0.f));
            *(uint4*)&As[buf][aw[i]] = q;
        }
    };

    // load one K-step's B frags: bc[k16][nt]
    auto loadB = [&](int kb, bf16x8 dst[4][2]) {
#pragma unroll
        for (int k16 = 0; k16 < 4; k16++)
#pragma unroll
            for (int nt = 0; nt < 2; nt++) {
                const int kq = kb * 2 + (k16 >> 1);
                const int kc = (k16 & 1) * 2 + hg;
                dst[k16][nt] = *(const bf16x8*)&WBsw[kq * 8192 + nb32[nt]
                                                    + ((kc ^ nsw[nt]) * 8)];
            }
    };

    // ---- prologue: build tile 0, load B for step 0
    {
        uint4 u[4], v[4];
#pragma unroll
        for (int i = 0; i < 4; i++) {
            u[i] = *(const uint4*)(up + i * 8);
            v[i] = *(const uint4*)(vp + i * 8);
        }
        build(0, u, v);
    }
    bf16x8 bc[4][2];
    loadB(0, bc);

    f32x16 acc[4][2] = {};

#pragma unroll
    for (int kb = 0; kb < 4; kb++) {
        const int cur = kb & 1;
        soft_barrier();                   // As[cur] built; lgkm drained only
        uint4 u[4], v[4];
        if (kb < 3) {
            const ushort_t* upn = up + (kb + 1) * 64;
            const ushort_t* vpn = vp + (kb + 1) * 64;
#pragma unroll
            for (int i = 0; i < 4; i++) {
                u[i] = *(const uint4*)(upn + i * 8);
                v[i] = *(const uint4*)(vpn + i * 8);
            }
        }
        // ---- 32-MFMA streak (32x32x16)
        __builtin_amdgcn_s_setprio(1);
#pragma unroll
        for (int k16 = 0; k16 < 4; k16++) {
            const int goff = (((k16 * 2 + hg) ^ r7) * 8);
            bf16x8 af[4];
#pragma unroll
            for (int mt = 0; mt < 4; mt++)
                af[mt] = *(const bf16x8*)&As[cur][abase[mt] + goff];
#pragma unroll
            for (int nt = 0; nt < 2; nt++)
#pragma unroll
                for (int mt = 0; mt < 4; mt++)
                    acc[mt][nt] = __builtin_amdgcn_mfma_f32_32x32x16_bf16(
                        af[mt], bc[k16][nt], acc[mt][nt], 0, 0, 0);
        }
        __builtin_amdgcn_s_setprio(0);
        if (kb < 3) {
            loadB(kb + 1, bc);            // in flight across next soft barrier
            build(cur ^ 1, u, v);         // u/v arrived under the streak
        }
    }

    // ---- Epilogue: bias+relu, sum 31 real slots per receiver, /31, bf16 out.
    // C/D layout: col = lane&31, row(slot) = (j&3) + 8*(j>>2) + 4*hg.
    // Slot 31 = reg 15 on hi half-wave only.
#pragma unroll
    for (int nt = 0; nt < 2; nt++) {
        const int col = w * 64 + nt * 32 + l31;
        const float bvf = b2[col];
#pragma unroll
        for (int mt = 0; mt < 4; mt++) {
            float sum = 0.f;
#pragma unroll
            for (int jj = 0; jj < 16; jj++) {
                float v = fmaxf(acc[mt][nt][jj] + bvf, 0.f);
                if (!(jj == 15 && hg == 1)) sum += v;   // skip slot 31
            }
            sum += __shfl_xor(sum, 32);
            if (lane < 32)
                agg[(size_t)(bb * 32 + g0 + mt) * 256 + col] =
                    f2bf(sum * (1.0f / 31.0f));
        }
    }
}

// ---------------------------------------------------------------------------
extern "C" void kernel_launch(void* const* d_in, const int* in_sizes, int n_in,
                              void* d_out, int out_size, void* d_ws, size_t ws_size,
                              hipStream_t stream)
{
    const float* x     = (const float*)d_in[0];
    const float* w_in1 = (const float*)d_in[3];
    const float* b_in1 = (const float*)d_in[4];
    const float* w_in2 = (const float*)d_in[5];
    const float* b_in2 = (const float*)d_in[6];
    const float* w_e1  = (const float*)d_in[7];
    const float* b_e1  = (const float*)d_in[8];
    const float* w_e2  = (const float*)d_in[9];
    const float* b_e2  = (const float*)d_in[10];
    const float* w_n1  = (const float*)d_in[11];
    const float* b_n1  = (const float*)d_in[12];
    const float* w_n2  = (const float*)d_in[13];
    const float* b_n2  = (const float*)d_in[14];

    char* ws = (char*)d_ws;
    size_t off = 0;
    auto alloc = [&](size_t n) { char* p = ws + off; off += (n + 255) & ~(size_t)255; return p; };

    ushort_t* wt  = (ushort_t*)alloc(7 * 65536 * sizeof(ushort_t));
    ushort_t* xb  = (ushort_t*)alloc(8192 * 256 * 2);
    ushort_t* UVb = (ushort_t*)alloc(8192 * 512 * 2);
    ushort_t* ag  = (ushort_t*)alloc(8192 * 256 * 2);
    (void)ws_size; (void)in_sizes; (void)n_in; (void)out_size;

    prep_all<<<1080, 256, 0, stream>>>(w_in1, w_in2, w_e1, w_e2, w_n1, w_n2, wt, x, xb);

    // pass 0 front: in1 -> in2 -> e1
    mlp_chain<1><<<256, 512, 0, stream>>>(xb,
        wt + 0 * 65536, b_in1, wt + 1 * 65536, b_in2, wt + 2 * 65536, b_e1, UVb);
    edge_fused<<<2048, 256, 0, stream>>>(UVb, wt + 4 * 65536, b_e2, ag);
    // pass 1 front: n1 -> n2 -> e1
    mlp_chain<1><<<256, 512, 0, stream>>>(ag,
        wt + 5 * 65536, b_n1, wt + 6 * 65536, b_n2, wt + 2 * 65536, b_e1, UVb);
    edge_fused<<<2048, 256, 0, stream>>>(UVb, wt + 4 * 65536, b_e2, ag);
    // final: n1 -> n2 (f32 out)
    mlp_chain<0><<<256, 512, 0, stream>>>(ag,
        wt + 5 * 65536, b_n1, wt + 6 * 65536, b_n2, nullptr, nullptr, d_out);
}